// Round 2
// baseline (3142.452 us; speedup 1.0000x reference)
//
#include <hip/hip_runtime.h>
#include <stdint.h>

#define T_DIM 8192
#define IN_DIM 1024
#define OUT_DIM 1024
#define M_DIM 128
#define C_DIM 32
#define CHUNK 2048
#define NCH 4

typedef __bf16 bf16x8 __attribute__((ext_vector_type(8)));
typedef float f32x4 __attribute__((ext_vector_type(4)));

__device__ inline unsigned short f2bf(float f) {
  unsigned int u = __float_as_uint(f);
  unsigned int r = (u + 0x7fffu + ((u >> 16) & 1u)) >> 16;
  return (unsigned short)r;
}
__device__ inline float bf2f(unsigned short h) {
  return __uint_as_float(((unsigned int)h) << 16);
}

// ---------------- float -> bf16 elementwise ----------------
__global__ __launch_bounds__(256) void f2bf_kernel(const float* __restrict__ in,
                                                   unsigned short* __restrict__ out, long n) {
  long i = (long)blockIdx.x * 256 + threadIdx.x;
  if (i < n) out[i] = f2bf(in[i]);
}

// ---- mix_w column-permute + bf16: B[o][k] = bf16(mix_w[o][ (k>>6)*64 + (k&1)*32 + ((k>>1)&31) ])
__global__ __launch_bounds__(256) void permconv_kernel(const float* __restrict__ w,
                                                       unsigned short* __restrict__ o, long n) {
  long i = (long)blockIdx.x * 256 + threadIdx.x;
  if (i >= n) return;
  long row = i >> 13;
  int k = (int)(i & 8191);
  int src = ((k >> 6) << 6) | ((k & 1) << 5) | ((k >> 1) & 31);
  o[i] = f2bf(w[(row << 13) + src]);
}

__global__ void concat_bias_kernel(const float* __restrict__ pre_b,
                                   const float* __restrict__ gin_b,
                                   float* __restrict__ bias_pg) {
  int i = threadIdx.x;
  bias_pg[i] = (i < 128) ? pre_b[i] : gin_b[i - 128];
}

// ---------------- bf16 MFMA GEMM (m97 structure) ----------------
// C[rows][N] = A[rows][K] * B[N][K]^T + bias
// epi: 0 = f32 out, 1 = bf16 sigmoid out, 2 = bf16 plain out
// grid = (N/128, rows/128), block = 256 (4 waves, each a 64x64 quadrant)
__global__ __launch_bounds__(256) void gemm_bf16_kernel(
    const unsigned short* __restrict__ A, const unsigned short* __restrict__ B,
    const float* __restrict__ bias, void* __restrict__ Cv,
    int Ndim, int K, int epi) {
  __shared__ __align__(16) unsigned short As[128 * 64];
  __shared__ __align__(16) unsigned short Bs[128 * 64];
  const int bn = blockIdx.x, bm = blockIdx.y;
  const int n0 = bn * 128, t0 = bm * 128;
  const int tid = threadIdx.x;
  const int lane = tid & 63, w = tid >> 6;
  const int wr = w >> 1, wc = w & 1;

  f32x4 acc[4][4] = {};

  const int srow = tid >> 3;        // 0..31
  const int skk = (tid & 7) * 8;    // 0..56
  const unsigned short* Ab = A + (size_t)(t0 + srow) * K + skk;
  const unsigned short* Bb = B + (size_t)(n0 + srow) * K + skk;

  for (int k0 = 0; k0 < K; k0 += 64) {
#pragma unroll
    for (int cc = 0; cc < 4; ++cc) {
      __builtin_amdgcn_global_load_lds(
          (const __attribute__((address_space(1))) void*)(Ab + k0 + (size_t)cc * 32 * K),
          (__attribute__((address_space(3))) void*)(As + cc * 2048 + w * 512), 16, 0, 0);
      __builtin_amdgcn_global_load_lds(
          (const __attribute__((address_space(1))) void*)(Bb + k0 + (size_t)cc * 32 * K),
          (__attribute__((address_space(3))) void*)(Bs + cc * 2048 + w * 512), 16, 0, 0);
    }
    __syncthreads();
    const int krd = (lane >> 4) * 8;
#pragma unroll
    for (int kk = 0; kk < 64; kk += 32) {
      bf16x8 af[4], bfr[4];
#pragma unroll
      for (int i = 0; i < 4; ++i) {
        af[i]  = *(const bf16x8*)&As[(wr * 64 + i * 16 + (lane & 15)) * 64 + kk + krd];
        bfr[i] = *(const bf16x8*)&Bs[(wc * 64 + i * 16 + (lane & 15)) * 64 + kk + krd];
      }
#pragma unroll
      for (int i = 0; i < 4; ++i)
#pragma unroll
        for (int j = 0; j < 4; ++j)
          acc[i][j] = __builtin_amdgcn_mfma_f32_16x16x32_bf16(af[i], bfr[j], acc[i][j], 0, 0, 0);
    }
    __syncthreads();
  }

  const int rbase = t0 + wr * 64 + ((lane >> 4) * 4);
  const int cbase = n0 + wc * 64 + (lane & 15);
#pragma unroll
  for (int j = 0; j < 4; ++j) {
    const int col = cbase + j * 16;
    const float bv = bias[col];
#pragma unroll
    for (int i = 0; i < 4; ++i) {
#pragma unroll
      for (int r = 0; r < 4; ++r) {
        float v = acc[i][j][r] + bv;
        size_t idx = (size_t)(rbase + i * 16 + r) * Ndim + col;
        if (epi == 0) {
          ((float*)Cv)[idx] = v;
        } else {
          if (epi == 1) v = 1.f / (1.f + expf(-v));
          ((unsigned short*)Cv)[idx] = f2bf(v);
        }
      }
    }
  }
}

// ---------------- gated_x = pre * sigmoid(gin) ----------------
__global__ __launch_bounds__(256) void gated_kernel(const float* __restrict__ tmp,
                                                    float* __restrict__ gated) {
  int i = blockIdx.x * 256 + threadIdx.x;  // T*128 total
  int t = i >> 7, m = i & 127;
  float p = tmp[t * 256 + m];
  float g = tmp[t * 256 + 128 + m];
  gated[i] = p / (1.f + expf(-g));
}

// ---------------- sequential scan over a T-chunk ----------------
// writes fp32 states (real-only or interleaved pairs per pair_mode) + packed bf16 pairs
__global__ __launch_bounds__(64) void scan_chunk_kernel(
    const float* __restrict__ gated, const int* __restrict__ done,
    const float* __restrict__ s0_re, const float* __restrict__ s0_im,
    const float* __restrict__ a, const float* __restrict__ b,
    float2* __restrict__ sbuf, float* __restrict__ out_states, int pair_mode,
    unsigned int* __restrict__ st_bf, int tbase) {
  int tid = blockIdx.x * 64 + threadIdx.x;  // 0..4095
  int m = tid >> 5, c = tid & 31;
  double mag = exp(-fabs((double)a[m]));
  float gr = (float)(mag * cos((double)b[c]));
  float gi = (float)(mag * sin((double)b[c]));
  float sr, si;
  if (tbase == 0) { sr = s0_re[tid]; si = s0_im[tid]; }
  else { float2 s = sbuf[tid]; sr = s.x; si = s.y; }
  for (int tt = 0; tt < CHUNK; ++tt) {
    int t = tbase + tt;
    float xv = gated[t * M_DIM + m];
    bool d = done[t] != 0;
    float pr = d ? 0.f : sr;
    float pi = d ? 0.f : si;
    float nr = fmaf(gr, pr, fmaf(-gi, pi, xv));
    float ni = fmaf(gi, pr, gr * pi);
    sr = nr; si = ni;
    if (pair_mode) {
      ((float2*)out_states)[(size_t)t * 4096 + tid] = make_float2(sr, si);
    } else {
      out_states[(size_t)t * 4096 + tid] = sr;
    }
    st_bf[(size_t)tt * 4096 + tid] = (unsigned int)f2bf(sr) | ((unsigned int)f2bf(si) << 16);
  }
  sbuf[tid] = make_float2(sr, si);
}

// ---------------- LN + gates epilogue, in-place over z ----------------
__global__ __launch_bounds__(256) void ln_kernel(float* __restrict__ z,
                                                 const unsigned short* __restrict__ gate,
                                                 const unsigned short* __restrict__ skip) {
  const int t = blockIdx.x;
  const int tid = threadIdx.x;
  __shared__ float sm[8];
  const size_t base = (size_t)t * 1024;
  float zg[4], g[4], sk[4];
  float sum = 0.f;
#pragma unroll
  for (int j = 0; j < 4; ++j) {
    int o = tid + j * 256;
    float zv = z[base + o];
    g[j] = bf2f(gate[base + o]);
    sk[j] = bf2f(skip[base + o]);
    zg[j] = zv * g[j];
    sum += zg[j];
  }
#pragma unroll
  for (int off = 32; off > 0; off >>= 1) sum += __shfl_down(sum, off, 64);
  if ((tid & 63) == 0) sm[tid >> 6] = sum;
  __syncthreads();
  const float mu = (sm[0] + sm[1] + sm[2] + sm[3]) * (1.f / 1024.f);
  float sq = 0.f;
#pragma unroll
  for (int j = 0; j < 4; ++j) { float d = zg[j] - mu; sq += d * d; }
#pragma unroll
  for (int off = 32; off > 0; off >>= 1) sq += __shfl_down(sq, off, 64);
  if ((tid & 63) == 0) sm[4 + (tid >> 6)] = sq;
  __syncthreads();
  const float var = (sm[4] + sm[5] + sm[6] + sm[7]) * (1.f / 1024.f);
  const float rstd = 1.f / sqrtf(var + 1e-5f);
#pragma unroll
  for (int j = 0; j < 4; ++j) {
    int o = tid + j * 256;
    z[base + o] = (zg[j] - mu) * rstd + sk[j] * (1.f - g[j]);
  }
}

extern "C" void kernel_launch(void* const* d_in, const int* in_sizes, int n_in,
                              void* d_out, int out_size, void* d_ws, size_t ws_size,
                              hipStream_t stream) {
  const float* x      = (const float*)d_in[0];
  const int*   done   = (const int*)d_in[1];
  const float* s0_re  = (const float*)d_in[2];
  const float* s0_im  = (const float*)d_in[3];
  const float* a      = (const float*)d_in[4];
  const float* b      = (const float*)d_in[5];
  const float* pre_w  = (const float*)d_in[6];
  const float* pre_b  = (const float*)d_in[7];
  const float* gin_w  = (const float*)d_in[8];
  const float* gin_b  = (const float*)d_in[9];
  const float* gout_w = (const float*)d_in[10];
  const float* gout_b = (const float*)d_in[11];
  const float* skip_w = (const float*)d_in[12];
  const float* skip_b = (const float*)d_in[13];
  const float* mix_w  = (const float*)d_in[14];
  const float* mix_b  = (const float*)d_in[15];

  float* out_f = (float*)d_out;                               // [T][1024]
  float* states_f = out_f + (size_t)T_DIM * OUT_DIM;          // real-only or float2 pairs
  // Hedge on harness packing of the complex64 states output:
  //  41943040 floats -> real part only; 75497472 -> interleaved (re,im) pairs.
  const int pair_mode = (out_size >= 75000000) ? 1 : 0;

  char* ws = (char*)d_ws;
  size_t off = 0;
  auto alloc = [&](size_t bytes) {
    void* p = ws + off;
    off = (off + bytes + 255) & ~(size_t)255;
    return p;
  };
  unsigned short* x_bf   = (unsigned short*)alloc((size_t)T_DIM * IN_DIM * 2);     // 16 MB
  unsigned short* Bmix   = (unsigned short*)alloc((size_t)OUT_DIM * 8192 * 2);     // 16 MB
  unsigned short* Wgout  = (unsigned short*)alloc((size_t)OUT_DIM * IN_DIM * 2);   // 2 MB
  unsigned short* Wskip  = (unsigned short*)alloc((size_t)OUT_DIM * IN_DIM * 2);   // 2 MB
  unsigned short* Wpg    = (unsigned short*)alloc((size_t)256 * IN_DIM * 2);       // 0.5 MB
  float* bias_pg         = (float*)alloc(256 * 4);
  // U region (32 MB): tmp_pg(8)+gated(4) early; gate_o(16)+skip_o(16) bf16 late
  char* U                = (char*)alloc((size_t)32 * 1024 * 1024);
  float* tmp_pg          = (float*)U;                           // [T][256] f32, 8 MB
  float* gated           = (float*)(U + 8 * 1024 * 1024);       // [T][128] f32, 4 MB
  unsigned short* gate_o = (unsigned short*)U;                  // [T][1024] bf16, 16 MB
  unsigned short* skip_o = (unsigned short*)(U + 16 * 1024 * 1024);
  unsigned short* st_bf  = (unsigned short*)alloc((size_t)CHUNK * 8192 * 2);       // 32 MB
  float2* sbuf           = (float2*)alloc(4096 * sizeof(float2));                  // 32 KB
  (void)ws_size; (void)n_in; (void)in_sizes;

  dim3 blk(256);
  long nx = (long)T_DIM * IN_DIM;
  f2bf_kernel<<<(unsigned)((nx + 255) / 256), blk, 0, stream>>>(x, x_bf, nx);
  permconv_kernel<<<32768, blk, 0, stream>>>(mix_w, Bmix, 8388608L);
  f2bf_kernel<<<4096, blk, 0, stream>>>(gout_w, Wgout, 1048576L);
  f2bf_kernel<<<4096, blk, 0, stream>>>(skip_w, Wskip, 1048576L);
  f2bf_kernel<<<512, blk, 0, stream>>>(pre_w, Wpg, 131072L);
  f2bf_kernel<<<512, blk, 0, stream>>>(gin_w, Wpg + 131072, 131072L);
  concat_bias_kernel<<<1, 256, 0, stream>>>(pre_b, gin_b, bias_pg);

  // gated_x path: [T,1024] @ [1024,256]^T -> tmp_pg, then elementwise
  gemm_bf16_kernel<<<dim3(2, 64), blk, 0, stream>>>(x_bf, Wpg, bias_pg, tmp_pg,
                                                    256, IN_DIM, 0);
  gated_kernel<<<(T_DIM * M_DIM) / 256, blk, 0, stream>>>(tmp_pg, gated);

  // scan chunks interleaved with per-chunk mix GEMM (st_bf reused, stream-ordered)
  for (int ch = 0; ch < NCH; ++ch) {
    scan_chunk_kernel<<<64, 64, 0, stream>>>(gated, done, s0_re, s0_im, a, b, sbuf,
                                             states_f, pair_mode,
                                             (unsigned int*)st_bf, ch * CHUNK);
    gemm_bf16_kernel<<<dim3(8, CHUNK / 128), blk, 0, stream>>>(
        st_bf, Bmix, mix_b, out_f + (size_t)ch * CHUNK * OUT_DIM, OUT_DIM, 8192, 0);
  }

  // gate_out = sigmoid(x @ gout_w^T + gout_b) -> bf16 ; skip -> bf16
  gemm_bf16_kernel<<<dim3(8, 64), blk, 0, stream>>>(x_bf, Wgout, gout_b, gate_o,
                                                    OUT_DIM, IN_DIM, 1);
  gemm_bf16_kernel<<<dim3(8, 64), blk, 0, stream>>>(x_bf, Wskip, skip_b, skip_o,
                                                    OUT_DIM, IN_DIM, 2);

  // LN + gating epilogue (in-place over z in d_out)
  ln_kernel<<<T_DIM, blk, 0, stream>>>(out_f, gate_o, skip_o);
}

// Round 3
// 596.615 us; speedup vs baseline: 5.2671x; 5.2671x over previous
//
#include <hip/hip_runtime.h>
#include <stdint.h>

#define T_DIM 8192
#define IN_DIM 1024
#define OUT_DIM 1024
#define M_DIM 128
#define C_DIM 32
#define SEG 64
#define NSEG (T_DIM / SEG)   // 128

typedef __bf16 bf16x8 __attribute__((ext_vector_type(8)));
typedef float f32x4 __attribute__((ext_vector_type(4)));

__device__ inline unsigned short f2bf(float f) {
  unsigned int u = __float_as_uint(f);
  unsigned int r = (u + 0x7fffu + ((u >> 16) & 1u)) >> 16;
  return (unsigned short)r;
}
__device__ inline float bf2f(unsigned short h) {
  return __uint_as_float(((unsigned int)h) << 16);
}

// ---------------- float -> bf16 elementwise ----------------
__global__ __launch_bounds__(256) void f2bf_kernel(const float* __restrict__ in,
                                                   unsigned short* __restrict__ out, long n) {
  long i = (long)blockIdx.x * 256 + threadIdx.x;
  if (i < n) out[i] = f2bf(in[i]);
}

// ---- mix_w column-permute + bf16: B[o][k] = bf16(mix_w[o][ (k>>6)*64 + (k&1)*32 + ((k>>1)&31) ])
__global__ __launch_bounds__(256) void permconv_kernel(const float* __restrict__ w,
                                                       unsigned short* __restrict__ o, long n) {
  long i = (long)blockIdx.x * 256 + threadIdx.x;
  if (i >= n) return;
  long row = i >> 13;
  int k = (int)(i & 8191);
  int src = ((k >> 6) << 6) | ((k & 1) << 5) | ((k >> 1) & 31);
  o[i] = f2bf(w[(row << 13) + src]);
}

__global__ void concat_bias_kernel(const float* __restrict__ pre_b,
                                   const float* __restrict__ gin_b,
                                   float* __restrict__ bias_pg) {
  int i = threadIdx.x;
  bias_pg[i] = (i < 128) ? pre_b[i] : gin_b[i - 128];
}

// ---------------- bf16 MFMA GEMM (m97 structure) ----------------
// C[rows][N] = A[rows][K] * B[N][K]^T + bias
// epi: 0 = f32 out, 1 = bf16 sigmoid out, 2 = bf16 plain out
__global__ __launch_bounds__(256) void gemm_bf16_kernel(
    const unsigned short* __restrict__ A, const unsigned short* __restrict__ B,
    const float* __restrict__ bias, void* __restrict__ Cv,
    int Ndim, int K, int epi) {
  __shared__ __align__(16) unsigned short As[128 * 64];
  __shared__ __align__(16) unsigned short Bs[128 * 64];
  const int bn = blockIdx.x, bm = blockIdx.y;
  const int n0 = bn * 128, t0 = bm * 128;
  const int tid = threadIdx.x;
  const int lane = tid & 63, w = tid >> 6;
  const int wr = w >> 1, wc = w & 1;

  f32x4 acc[4][4] = {};

  const int srow = tid >> 3;        // 0..31
  const int skk = (tid & 7) * 8;    // 0..56
  const unsigned short* Ab = A + (size_t)(t0 + srow) * K + skk;
  const unsigned short* Bb = B + (size_t)(n0 + srow) * K + skk;

  for (int k0 = 0; k0 < K; k0 += 64) {
#pragma unroll
    for (int cc = 0; cc < 4; ++cc) {
      __builtin_amdgcn_global_load_lds(
          (const __attribute__((address_space(1))) void*)(Ab + k0 + (size_t)cc * 32 * K),
          (__attribute__((address_space(3))) void*)(As + cc * 2048 + w * 512), 16, 0, 0);
      __builtin_amdgcn_global_load_lds(
          (const __attribute__((address_space(1))) void*)(Bb + k0 + (size_t)cc * 32 * K),
          (__attribute__((address_space(3))) void*)(Bs + cc * 2048 + w * 512), 16, 0, 0);
    }
    __syncthreads();
    const int krd = (lane >> 4) * 8;
#pragma unroll
    for (int kk = 0; kk < 64; kk += 32) {
      bf16x8 af[4], bfr[4];
#pragma unroll
      for (int i = 0; i < 4; ++i) {
        af[i]  = *(const bf16x8*)&As[(wr * 64 + i * 16 + (lane & 15)) * 64 + kk + krd];
        bfr[i] = *(const bf16x8*)&Bs[(wc * 64 + i * 16 + (lane & 15)) * 64 + kk + krd];
      }
#pragma unroll
      for (int i = 0; i < 4; ++i)
#pragma unroll
        for (int j = 0; j < 4; ++j)
          acc[i][j] = __builtin_amdgcn_mfma_f32_16x16x32_bf16(af[i], bfr[j], acc[i][j], 0, 0, 0);
    }
    __syncthreads();
  }

  const int rbase = t0 + wr * 64 + ((lane >> 4) * 4);
  const int cbase = n0 + wc * 64 + (lane & 15);
#pragma unroll
  for (int j = 0; j < 4; ++j) {
    const int col = cbase + j * 16;
    const float bv = bias[col];
#pragma unroll
    for (int i = 0; i < 4; ++i) {
#pragma unroll
      for (int r = 0; r < 4; ++r) {
        float v = acc[i][j][r] + bv;
        size_t idx = (size_t)(rbase + i * 16 + r) * Ndim + col;
        if (epi == 0) {
          ((float*)Cv)[idx] = v;
        } else {
          if (epi == 1) v = 1.f / (1.f + expf(-v));
          ((unsigned short*)Cv)[idx] = f2bf(v);
        }
      }
    }
  }
}

// ---------------- gated_x = pre * sigmoid(gin) ----------------
__global__ __launch_bounds__(256) void gated_kernel(const float* __restrict__ tmp,
                                                    float* __restrict__ gated) {
  int i = blockIdx.x * 256 + threadIdx.x;  // T*128 total
  int t = i >> 7, m = i & 127;
  float p = tmp[t * 256 + m];
  float g = tmp[t * 256 + 128 + m];
  gated[i] = p / (1.f + expf(-g));
}

// ================= parallel scan =================
// P1: per-segment affine carry (A, B) with zero init.
// thread -> (segment, lane); lane = m*32+c
__global__ __launch_bounds__(256) void scan_p1_kernel(
    const float* __restrict__ gated, const int* __restrict__ done,
    const float* __restrict__ a, const float* __restrict__ b,
    float2* __restrict__ carryA, float2* __restrict__ carryB) {
  int gid = blockIdx.x * 256 + threadIdx.x;   // 0 .. NSEG*4096-1
  int seg = gid >> 12;
  int tid = gid & 4095;
  int m = tid >> 5, c = tid & 31;
  double mag = exp(-fabs((double)a[m]));
  float gr = (float)(mag * cos((double)b[c]));
  float gi = (float)(mag * sin((double)b[c]));
  int t0 = seg * SEG;
  float sr = 0.f, si = 0.f, keep_all = 1.f;
  for (int tt = 0; tt < SEG; ++tt) {
    int t = t0 + tt;
    float xv = gated[t * M_DIM + m];
    bool d = done[t] != 0;
    float pr = d ? 0.f : sr;
    float pi = d ? 0.f : si;
    if (d) keep_all = 0.f;
    sr = fmaf(gr, pr, fmaf(-gi, pi, xv));
    si = fmaf(gi, pr, gr * pi);
  }
  carryB[(size_t)seg * 4096 + tid] = make_float2(sr, si);
  double angL = (double)b[c] * (double)SEG;
  double magL = exp(-fabs((double)a[m]) * (double)SEG);
  carryA[(size_t)seg * 4096 + tid] =
      make_float2(keep_all * (float)(magL * cos(angL)), keep_all * (float)(magL * sin(angL)));
}

// P2: sequential carry scan over segments; writes segment-start states into carryB (in place).
__global__ __launch_bounds__(256) void scan_p2_kernel(
    const float2* __restrict__ carryA, float2* __restrict__ carryB,
    const float* __restrict__ s0_re, const float* __restrict__ s0_im) {
  int tid = blockIdx.x * 256 + threadIdx.x;   // 0..4095
  float sr = s0_re[tid], si = s0_im[tid];
  for (int p = 0; p < NSEG; ++p) {
    size_t idx = (size_t)p * 4096 + tid;
    float2 A = carryA[idx];
    float2 B = carryB[idx];
    carryB[idx] = make_float2(sr, si);        // segment start state
    float nr = fmaf(A.x, sr, fmaf(-A.y, si, B.x));
    float ni = fmaf(A.y, sr, fmaf(A.x, si, B.y));
    sr = nr; si = ni;
  }
}

// P3: re-run each segment from its start state; write fp32 states + packed bf16.
__global__ __launch_bounds__(256) void scan_p3_kernel(
    const float* __restrict__ gated, const int* __restrict__ done,
    const float* __restrict__ a, const float* __restrict__ b,
    const float2* __restrict__ segstart,
    float* __restrict__ out_states, int pair_mode,
    unsigned int* __restrict__ st_bf, int tbase, int nseg_chunk) {
  int gid = blockIdx.x * 256 + threadIdx.x;   // 0 .. nseg_chunk*4096-1
  int segl = gid >> 12;
  int tid = gid & 4095;
  int m = tid >> 5, c = tid & 31;
  int seg = tbase / SEG + segl;
  double mag = exp(-fabs((double)a[m]));
  float gr = (float)(mag * cos((double)b[c]));
  float gi = (float)(mag * sin((double)b[c]));
  float2 s = segstart[(size_t)seg * 4096 + tid];
  float sr = s.x, si = s.y;
  int t0 = seg * SEG;
  for (int tt = 0; tt < SEG; ++tt) {
    int t = t0 + tt;
    float xv = gated[t * M_DIM + m];
    bool d = done[t] != 0;
    float pr = d ? 0.f : sr;
    float pi = d ? 0.f : si;
    sr = fmaf(gr, pr, fmaf(-gi, pi, xv));
    si = fmaf(gi, pr, gr * pi);
    if (pair_mode) {
      ((float2*)out_states)[(size_t)t * 4096 + tid] = make_float2(sr, si);
    } else {
      out_states[(size_t)t * 4096 + tid] = sr;
    }
    st_bf[(size_t)(t - tbase) * 4096 + tid] =
        (unsigned int)f2bf(sr) | ((unsigned int)f2bf(si) << 16);
  }
}

// ---------------- LN + gates epilogue, in-place over z ----------------
__global__ __launch_bounds__(256) void ln_kernel(float* __restrict__ z,
                                                 const unsigned short* __restrict__ gate,
                                                 const unsigned short* __restrict__ skip) {
  const int t = blockIdx.x;
  const int tid = threadIdx.x;
  __shared__ float sm[8];
  const size_t base = (size_t)t * 1024;
  float zg[4], g[4], sk[4];
  float sum = 0.f;
#pragma unroll
  for (int j = 0; j < 4; ++j) {
    int o = tid + j * 256;
    float zv = z[base + o];
    g[j] = bf2f(gate[base + o]);
    sk[j] = bf2f(skip[base + o]);
    zg[j] = zv * g[j];
    sum += zg[j];
  }
#pragma unroll
  for (int off = 32; off > 0; off >>= 1) sum += __shfl_down(sum, off, 64);
  if ((tid & 63) == 0) sm[tid >> 6] = sum;
  __syncthreads();
  const float mu = (sm[0] + sm[1] + sm[2] + sm[3]) * (1.f / 1024.f);
  float sq = 0.f;
#pragma unroll
  for (int j = 0; j < 4; ++j) { float d = zg[j] - mu; sq += d * d; }
#pragma unroll
  for (int off = 32; off > 0; off >>= 1) sq += __shfl_down(sq, off, 64);
  if ((tid & 63) == 0) sm[4 + (tid >> 6)] = sq;
  __syncthreads();
  const float var = (sm[4] + sm[5] + sm[6] + sm[7]) * (1.f / 1024.f);
  const float rstd = 1.f / sqrtf(var + 1e-5f);
#pragma unroll
  for (int j = 0; j < 4; ++j) {
    int o = tid + j * 256;
    z[base + o] = (zg[j] - mu) * rstd + sk[j] * (1.f - g[j]);
  }
}

extern "C" void kernel_launch(void* const* d_in, const int* in_sizes, int n_in,
                              void* d_out, int out_size, void* d_ws, size_t ws_size,
                              hipStream_t stream) {
  const float* x      = (const float*)d_in[0];
  const int*   done   = (const int*)d_in[1];
  const float* s0_re  = (const float*)d_in[2];
  const float* s0_im  = (const float*)d_in[3];
  const float* a      = (const float*)d_in[4];
  const float* b      = (const float*)d_in[5];
  const float* pre_w  = (const float*)d_in[6];
  const float* pre_b  = (const float*)d_in[7];
  const float* gin_w  = (const float*)d_in[8];
  const float* gin_b  = (const float*)d_in[9];
  const float* gout_w = (const float*)d_in[10];
  const float* gout_b = (const float*)d_in[11];
  const float* skip_w = (const float*)d_in[12];
  const float* skip_b = (const float*)d_in[13];
  const float* mix_w  = (const float*)d_in[14];
  const float* mix_b  = (const float*)d_in[15];

  float* out_f = (float*)d_out;                               // [T][1024]
  float* states_f = out_f + (size_t)T_DIM * OUT_DIM;          // real-only or float2 pairs
  const int pair_mode = (out_size >= 75000000) ? 1 : 0;

  char* ws = (char*)d_ws;
  size_t off = 0;
  auto alloc = [&](size_t bytes) {
    void* p = ws + off;
    off = (off + bytes + 255) & ~(size_t)255;
    return p;
  };
  unsigned short* x_bf   = (unsigned short*)alloc((size_t)T_DIM * IN_DIM * 2);     // 16 MB
  unsigned short* Bmix   = (unsigned short*)alloc((size_t)OUT_DIM * 8192 * 2);     // 16 MB
  unsigned short* Wgout  = (unsigned short*)alloc((size_t)OUT_DIM * IN_DIM * 2);   // 2 MB
  unsigned short* Wskip  = (unsigned short*)alloc((size_t)OUT_DIM * IN_DIM * 2);   // 2 MB
  unsigned short* Wpg    = (unsigned short*)alloc((size_t)256 * IN_DIM * 2);       // 0.5 MB
  float* bias_pg         = (float*)alloc(256 * 4);
  // U region (32 MB): tmp_pg(8)+gated(4) early; gate_o(16)+skip_o(16) bf16 late
  char* U                = (char*)alloc((size_t)32 * 1024 * 1024);
  float* tmp_pg          = (float*)U;                           // [T][256] f32, 8 MB
  float* gated           = (float*)(U + 8 * 1024 * 1024);       // [T][128] f32, 4 MB
  unsigned short* gate_o = (unsigned short*)U;                  // [T][1024] bf16, 16 MB
  unsigned short* skip_o = (unsigned short*)(U + 16 * 1024 * 1024);
  float2* carryA         = (float2*)alloc((size_t)NSEG * 4096 * 8);                // 4 MB
  float2* carryB         = (float2*)alloc((size_t)NSEG * 4096 * 8);                // 4 MB (-> segstart)
  // mix-GEMM chunk size chosen from remaining scratch (st_bf = CHUNK*8192*2 bytes)
  size_t remain = (ws_size > off) ? (ws_size - off) : 0;
  int chunk;
  if (remain >= (size_t)4096 * 8192 * 2 + 4096) chunk = 4096;
  else if (remain >= (size_t)2048 * 8192 * 2 + 4096) chunk = 2048;
  else chunk = 1024;
  unsigned short* st_bf  = (unsigned short*)alloc((size_t)chunk * 8192 * 2);
  (void)n_in; (void)in_sizes;

  dim3 blk(256);
  long nx = (long)T_DIM * IN_DIM;
  f2bf_kernel<<<(unsigned)((nx + 255) / 256), blk, 0, stream>>>(x, x_bf, nx);
  permconv_kernel<<<32768, blk, 0, stream>>>(mix_w, Bmix, 8388608L);
  f2bf_kernel<<<4096, blk, 0, stream>>>(gout_w, Wgout, 1048576L);
  f2bf_kernel<<<4096, blk, 0, stream>>>(skip_w, Wskip, 1048576L);
  f2bf_kernel<<<512, blk, 0, stream>>>(pre_w, Wpg, 131072L);
  f2bf_kernel<<<512, blk, 0, stream>>>(gin_w, Wpg + 131072, 131072L);
  concat_bias_kernel<<<1, 256, 0, stream>>>(pre_b, gin_b, bias_pg);

  // gated_x path: [T,1024] @ [1024,256]^T -> tmp_pg, then elementwise
  gemm_bf16_kernel<<<dim3(2, 64), blk, 0, stream>>>(x_bf, Wpg, bias_pg, tmp_pg,
                                                    256, IN_DIM, 0);
  gated_kernel<<<(T_DIM * M_DIM) / 256, blk, 0, stream>>>(tmp_pg, gated);

  // parallel scan: P1 (segment carries), P2 (carry scan -> segment starts)
  scan_p1_kernel<<<NSEG * 16, blk, 0, stream>>>(gated, done, a, b, carryA, carryB);
  scan_p2_kernel<<<16, blk, 0, stream>>>(carryA, carryB, s0_re, s0_im);

  // per chunk: P3 (write states + bf16) then mix GEMM
  for (int tbase = 0; tbase < T_DIM; tbase += chunk) {
    int nseg_chunk = chunk / SEG;
    scan_p3_kernel<<<nseg_chunk * 16, blk, 0, stream>>>(gated, done, a, b, carryB,
                                                        states_f, pair_mode,
                                                        (unsigned int*)st_bf, tbase, nseg_chunk);
    gemm_bf16_kernel<<<dim3(8, chunk / 128), blk, 0, stream>>>(
        st_bf, Bmix, mix_b, out_f + (size_t)tbase * OUT_DIM, OUT_DIM, 8192, 0);
  }

  // gate_out = sigmoid(x @ gout_w^T + gout_b) -> bf16 ; skip -> bf16
  gemm_bf16_kernel<<<dim3(8, 64), blk, 0, stream>>>(x_bf, Wgout, gout_b, gate_o,
                                                    OUT_DIM, IN_DIM, 1);
  gemm_bf16_kernel<<<dim3(8, 64), blk, 0, stream>>>(x_bf, Wskip, skip_b, skip_o,
                                                    OUT_DIM, IN_DIM, 2);

  // LN + gating epilogue (in-place over z in d_out)
  ln_kernel<<<T_DIM, blk, 0, stream>>>(out_f, gate_o, skip_o);
}

// Round 4
// 536.393 us; speedup vs baseline: 5.8585x; 1.1123x over previous
//
#include <hip/hip_runtime.h>
#include <stdint.h>

#define T_DIM 8192
#define IN_DIM 1024
#define OUT_DIM 1024
#define M_DIM 128
#define C_DIM 32
#define SEG 64
#define NSEG (T_DIM / SEG)   // 128
#define CHUNK 2048
#define NCH (T_DIM / CHUNK)  // 4
#define KS 4
#define KSLICE (8192 / KS)   // 2048

typedef __bf16 bf16x8 __attribute__((ext_vector_type(8)));
typedef float f32x4 __attribute__((ext_vector_type(4)));

__device__ inline unsigned short f2bf(float f) {
  unsigned int u = __float_as_uint(f);
  unsigned int r = (u + 0x7fffu + ((u >> 16) & 1u)) >> 16;
  return (unsigned short)r;
}
__device__ inline float bf2f(unsigned short h) {
  return __uint_as_float(((unsigned int)h) << 16);
}

// ---------------- float -> bf16 elementwise ----------------
__global__ __launch_bounds__(256) void f2bf_kernel(const float* __restrict__ in,
                                                   unsigned short* __restrict__ out, long n) {
  long i = (long)blockIdx.x * 256 + threadIdx.x;
  if (i < n) out[i] = f2bf(in[i]);
}

// ---- mix_w column-permute + bf16: B[o][k] = bf16(mix_w[o][ (k>>6)*64 + (k&1)*32 + ((k>>1)&31) ])
__global__ __launch_bounds__(256) void permconv_kernel(const float* __restrict__ w,
                                                       unsigned short* __restrict__ o, long n) {
  long i = (long)blockIdx.x * 256 + threadIdx.x;
  if (i >= n) return;
  long row = i >> 13;
  int k = (int)(i & 8191);
  int src = ((k >> 6) << 6) | ((k & 1) << 5) | ((k >> 1) & 31);
  o[i] = f2bf(w[(row << 13) + src]);
}

// concat two bias vectors
__global__ void concat2_kernel(const float* __restrict__ s0, int n0,
                               const float* __restrict__ s1, int n1,
                               float* __restrict__ dst) {
  int i = blockIdx.x * 256 + threadIdx.x;
  if (i < n0) dst[i] = s0[i];
  else if (i < n0 + n1) dst[i] = s1[i - n0];
}

// ---------------- bf16 MFMA GEMM (m97 structure) ----------------
// C[rows][N] = A[rows][K] * B[N][K]^T + bias
// epi: 0 = f32 out, 2 = bf16 plain out
__global__ __launch_bounds__(256) void gemm_bf16_kernel(
    const unsigned short* __restrict__ A, const unsigned short* __restrict__ B,
    const float* __restrict__ bias, void* __restrict__ Cv,
    int Ndim, int K, int epi) {
  __shared__ __align__(16) unsigned short As[128 * 64];
  __shared__ __align__(16) unsigned short Bs[128 * 64];
  const int bn = blockIdx.x, bm = blockIdx.y;
  const int n0 = bn * 128, t0 = bm * 128;
  const int tid = threadIdx.x;
  const int lane = tid & 63, w = tid >> 6;
  const int wr = w >> 1, wc = w & 1;

  f32x4 acc[4][4] = {};

  const int srow = tid >> 3;        // 0..31
  const int skk = (tid & 7) * 8;    // 0..56
  const unsigned short* Ab = A + (size_t)(t0 + srow) * K + skk;
  const unsigned short* Bb = B + (size_t)(n0 + srow) * K + skk;

  for (int k0 = 0; k0 < K; k0 += 64) {
#pragma unroll
    for (int cc = 0; cc < 4; ++cc) {
      __builtin_amdgcn_global_load_lds(
          (const __attribute__((address_space(1))) void*)(Ab + k0 + (size_t)cc * 32 * K),
          (__attribute__((address_space(3))) void*)(As + cc * 2048 + w * 512), 16, 0, 0);
      __builtin_amdgcn_global_load_lds(
          (const __attribute__((address_space(1))) void*)(Bb + k0 + (size_t)cc * 32 * K),
          (__attribute__((address_space(3))) void*)(Bs + cc * 2048 + w * 512), 16, 0, 0);
    }
    __syncthreads();
    const int krd = (lane >> 4) * 8;
#pragma unroll
    for (int kk = 0; kk < 64; kk += 32) {
      bf16x8 af[4], bfr[4];
#pragma unroll
      for (int i = 0; i < 4; ++i) {
        af[i]  = *(const bf16x8*)&As[(wr * 64 + i * 16 + (lane & 15)) * 64 + kk + krd];
        bfr[i] = *(const bf16x8*)&Bs[(wc * 64 + i * 16 + (lane & 15)) * 64 + kk + krd];
      }
#pragma unroll
      for (int i = 0; i < 4; ++i)
#pragma unroll
        for (int j = 0; j < 4; ++j)
          acc[i][j] = __builtin_amdgcn_mfma_f32_16x16x32_bf16(af[i], bfr[j], acc[i][j], 0, 0, 0);
    }
    __syncthreads();
  }

  const int rbase = t0 + wr * 64 + ((lane >> 4) * 4);
  const int cbase = n0 + wc * 64 + (lane & 15);
#pragma unroll
  for (int j = 0; j < 4; ++j) {
    const int col = cbase + j * 16;
    const float bv = bias[col];
#pragma unroll
    for (int i = 0; i < 4; ++i) {
#pragma unroll
      for (int r = 0; r < 4; ++r) {
        float v = acc[i][j][r] + bv;
        size_t idx = (size_t)(rbase + i * 16 + r) * Ndim + col;
        if (epi == 0) ((float*)Cv)[idx] = v;
        else          ((unsigned short*)Cv)[idx] = f2bf(v);
      }
    }
  }
}

// ---------------- split-K mix GEMM: partials[ks][CHUNK][1024] ----------------
// A [CHUNK][8192] bf16, B [1024][8192] bf16. Flat grid 8*16*KS = 512, XCD-swizzled.
__global__ __launch_bounds__(256) void gemm_splitk_kernel(
    const unsigned short* __restrict__ A, const unsigned short* __restrict__ B,
    float* __restrict__ partials) {
  __shared__ __align__(16) unsigned short As[128 * 64];
  __shared__ __align__(16) unsigned short Bs[128 * 64];
  const int bfl = blockIdx.x;                    // 0..511
  const int wid = ((bfl & 7) << 6) | (bfl >> 3); // bijective XCD swizzle (nwg=512)
  const int bn = wid & 7;
  const int bm = (wid >> 3) & 15;
  const int ks = wid >> 7;
  const int n0 = bn * 128, t0 = bm * 128;
  const int tid = threadIdx.x;
  const int lane = tid & 63, w = tid >> 6;
  const int wr = w >> 1, wc = w & 1;

  f32x4 acc[4][4] = {};

  const int srow = tid >> 3;
  const int skk = (tid & 7) * 8;
  const unsigned short* Ab = A + (size_t)(t0 + srow) * 8192 + ks * KSLICE + skk;
  const unsigned short* Bb = B + (size_t)(n0 + srow) * 8192 + ks * KSLICE + skk;

  for (int k0 = 0; k0 < KSLICE; k0 += 64) {
#pragma unroll
    for (int cc = 0; cc < 4; ++cc) {
      __builtin_amdgcn_global_load_lds(
          (const __attribute__((address_space(1))) void*)(Ab + k0 + (size_t)cc * 32 * 8192),
          (__attribute__((address_space(3))) void*)(As + cc * 2048 + w * 512), 16, 0, 0);
      __builtin_amdgcn_global_load_lds(
          (const __attribute__((address_space(1))) void*)(Bb + k0 + (size_t)cc * 32 * 8192),
          (__attribute__((address_space(3))) void*)(Bs + cc * 2048 + w * 512), 16, 0, 0);
    }
    __syncthreads();
    const int krd = (lane >> 4) * 8;
#pragma unroll
    for (int kk = 0; kk < 64; kk += 32) {
      bf16x8 af[4], bfr[4];
#pragma unroll
      for (int i = 0; i < 4; ++i) {
        af[i]  = *(const bf16x8*)&As[(wr * 64 + i * 16 + (lane & 15)) * 64 + kk + krd];
        bfr[i] = *(const bf16x8*)&Bs[(wc * 64 + i * 16 + (lane & 15)) * 64 + kk + krd];
      }
#pragma unroll
      for (int i = 0; i < 4; ++i)
#pragma unroll
        for (int j = 0; j < 4; ++j)
          acc[i][j] = __builtin_amdgcn_mfma_f32_16x16x32_bf16(af[i], bfr[j], acc[i][j], 0, 0, 0);
    }
    __syncthreads();
  }

  float* Cp = partials + (size_t)ks * CHUNK * 1024;
  const int rbase = t0 + wr * 64 + ((lane >> 4) * 4);
  const int cbase = n0 + wc * 64 + (lane & 15);
#pragma unroll
  for (int j = 0; j < 4; ++j) {
    const int col = cbase + j * 16;
#pragma unroll
    for (int i = 0; i < 4; ++i)
#pragma unroll
      for (int r = 0; r < 4; ++r)
        Cp[(size_t)(rbase + i * 16 + r) * 1024 + col] = acc[i][j][r];
  }
}

// reduce KS partials + bias -> out chunk (float4 vectorized)
__global__ __launch_bounds__(256) void reduce_kernel(const f32x4* __restrict__ partials,
                                                     const f32x4* __restrict__ bias4,
                                                     f32x4* __restrict__ outc) {
  int i = blockIdx.x * 256 + threadIdx.x;       // 0 .. CHUNK*256-1
  const size_t stride = (size_t)CHUNK * 256;
  f32x4 s = partials[i];
#pragma unroll
  for (int p = 1; p < KS; ++p) s += partials[(size_t)p * stride + i];
  s += bias4[i & 255];
  outc[i] = s;
}

// ---------------- gated_x = pre * sigmoid(gin) ----------------
__global__ __launch_bounds__(256) void gated_kernel(const float* __restrict__ tmp,
                                                    float* __restrict__ gated) {
  int i = blockIdx.x * 256 + threadIdx.x;  // T*128 total
  int t = i >> 7, m = i & 127;
  float p = tmp[t * 256 + m];
  float g = tmp[t * 256 + 128 + m];
  gated[i] = p / (1.f + expf(-g));
}

// ================= parallel scan =================
__global__ __launch_bounds__(256) void scan_p1_kernel(
    const float* __restrict__ gated, const int* __restrict__ done,
    const float* __restrict__ a, const float* __restrict__ b,
    float2* __restrict__ carryA, float2* __restrict__ carryB) {
  int gid = blockIdx.x * 256 + threadIdx.x;
  int seg = gid >> 12;
  int tid = gid & 4095;
  int m = tid >> 5, c = tid & 31;
  double mag = exp(-fabs((double)a[m]));
  float gr = (float)(mag * cos((double)b[c]));
  float gi = (float)(mag * sin((double)b[c]));
  int t0 = seg * SEG;
  float sr = 0.f, si = 0.f, keep_all = 1.f;
  for (int tt = 0; tt < SEG; ++tt) {
    int t = t0 + tt;
    float xv = gated[t * M_DIM + m];
    bool d = done[t] != 0;
    float pr = d ? 0.f : sr;
    float pi = d ? 0.f : si;
    if (d) keep_all = 0.f;
    sr = fmaf(gr, pr, fmaf(-gi, pi, xv));
    si = fmaf(gi, pr, gr * pi);
  }
  carryB[(size_t)seg * 4096 + tid] = make_float2(sr, si);
  double angL = (double)b[c] * (double)SEG;
  double magL = exp(-fabs((double)a[m]) * (double)SEG);
  carryA[(size_t)seg * 4096 + tid] =
      make_float2(keep_all * (float)(magL * cos(angL)), keep_all * (float)(magL * sin(angL)));
}

__global__ __launch_bounds__(256) void scan_p2_kernel(
    const float2* __restrict__ carryA, float2* __restrict__ carryB,
    const float* __restrict__ s0_re, const float* __restrict__ s0_im) {
  int tid = blockIdx.x * 256 + threadIdx.x;
  float sr = s0_re[tid], si = s0_im[tid];
  for (int p = 0; p < NSEG; ++p) {
    size_t idx = (size_t)p * 4096 + tid;
    float2 A = carryA[idx];
    float2 B = carryB[idx];
    carryB[idx] = make_float2(sr, si);
    float nr = fmaf(A.x, sr, fmaf(-A.y, si, B.x));
    float ni = fmaf(A.y, sr, fmaf(A.x, si, B.y));
    sr = nr; si = ni;
  }
}

__global__ __launch_bounds__(256) void scan_p3_kernel(
    const float* __restrict__ gated, const int* __restrict__ done,
    const float* __restrict__ a, const float* __restrict__ b,
    const float2* __restrict__ segstart,
    float* __restrict__ out_states, int pair_mode,
    unsigned int* __restrict__ st_bf, int tbase, int nseg_chunk) {
  int gid = blockIdx.x * 256 + threadIdx.x;
  int segl = gid >> 12;
  int tid = gid & 4095;
  int m = tid >> 5, c = tid & 31;
  int seg = tbase / SEG + segl;
  double mag = exp(-fabs((double)a[m]));
  float gr = (float)(mag * cos((double)b[c]));
  float gi = (float)(mag * sin((double)b[c]));
  float2 s = segstart[(size_t)seg * 4096 + tid];
  float sr = s.x, si = s.y;
  int t0 = seg * SEG;
  for (int tt = 0; tt < SEG; ++tt) {
    int t = t0 + tt;
    float xv = gated[t * M_DIM + m];
    bool d = done[t] != 0;
    float pr = d ? 0.f : sr;
    float pi = d ? 0.f : si;
    sr = fmaf(gr, pr, fmaf(-gi, pi, xv));
    si = fmaf(gi, pr, gr * pi);
    if (pair_mode) {
      ((float2*)out_states)[(size_t)t * 4096 + tid] = make_float2(sr, si);
    } else {
      out_states[(size_t)t * 4096 + tid] = sr;
    }
    st_bf[(size_t)(t - tbase) * 4096 + tid] =
        (unsigned int)f2bf(sr) | ((unsigned int)f2bf(si) << 16);
  }
}

// ---------------- LN + gates epilogue; gs = [T][2048] raw logits bf16 ----------------
__global__ __launch_bounds__(256) void ln_kernel(float* __restrict__ z,
                                                 const unsigned short* __restrict__ gs) {
  const int t = blockIdx.x;
  const int tid = threadIdx.x;
  __shared__ float sm[8];
  const size_t base = (size_t)t * 1024;
  const size_t base2 = (size_t)t * 2048;
  float zg[4], g[4], sk[4];
  float sum = 0.f;
#pragma unroll
  for (int j = 0; j < 4; ++j) {
    int o = tid + j * 256;
    float zv = z[base + o];
    g[j] = 1.f / (1.f + expf(-bf2f(gs[base2 + o])));
    sk[j] = bf2f(gs[base2 + 1024 + o]);
    zg[j] = zv * g[j];
    sum += zg[j];
  }
#pragma unroll
  for (int off = 32; off > 0; off >>= 1) sum += __shfl_down(sum, off, 64);
  if ((tid & 63) == 0) sm[tid >> 6] = sum;
  __syncthreads();
  const float mu = (sm[0] + sm[1] + sm[2] + sm[3]) * (1.f / 1024.f);
  float sq = 0.f;
#pragma unroll
  for (int j = 0; j < 4; ++j) { float d = zg[j] - mu; sq += d * d; }
#pragma unroll
  for (int off = 32; off > 0; off >>= 1) sq += __shfl_down(sq, off, 64);
  if ((tid & 63) == 0) sm[4 + (tid >> 6)] = sq;
  __syncthreads();
  const float var = (sm[4] + sm[5] + sm[6] + sm[7]) * (1.f / 1024.f);
  const float rstd = 1.f / sqrtf(var + 1e-5f);
#pragma unroll
  for (int j = 0; j < 4; ++j) {
    int o = tid + j * 256;
    z[base + o] = (zg[j] - mu) * rstd + sk[j] * (1.f - g[j]);
  }
}

extern "C" void kernel_launch(void* const* d_in, const int* in_sizes, int n_in,
                              void* d_out, int out_size, void* d_ws, size_t ws_size,
                              hipStream_t stream) {
  const float* x      = (const float*)d_in[0];
  const int*   done   = (const int*)d_in[1];
  const float* s0_re  = (const float*)d_in[2];
  const float* s0_im  = (const float*)d_in[3];
  const float* a      = (const float*)d_in[4];
  const float* b      = (const float*)d_in[5];
  const float* pre_w  = (const float*)d_in[6];
  const float* pre_b  = (const float*)d_in[7];
  const float* gin_w  = (const float*)d_in[8];
  const float* gin_b  = (const float*)d_in[9];
  const float* gout_w = (const float*)d_in[10];
  const float* gout_b = (const float*)d_in[11];
  const float* skip_w = (const float*)d_in[12];
  const float* skip_b = (const float*)d_in[13];
  const float* mix_w  = (const float*)d_in[14];
  const float* mix_b  = (const float*)d_in[15];

  float* out_f = (float*)d_out;                               // [T][1024]
  float* states_f = out_f + (size_t)T_DIM * OUT_DIM;
  const int pair_mode = (out_size >= 75000000) ? 1 : 0;

  char* ws = (char*)d_ws;
  size_t off = 0;
  auto alloc = [&](size_t bytes) {
    void* p = ws + off;
    off = (off + bytes + 255) & ~(size_t)255;
    return p;
  };
  unsigned short* x_bf   = (unsigned short*)alloc((size_t)T_DIM * IN_DIM * 2);     // 16 MB
  unsigned short* Bmix   = (unsigned short*)alloc((size_t)OUT_DIM * 8192 * 2);     // 16 MB
  unsigned short* Wgs    = (unsigned short*)alloc((size_t)2048 * IN_DIM * 2);      // 4 MB
  unsigned short* Wpg    = (unsigned short*)alloc((size_t)256 * IN_DIM * 2);       // 0.5 MB
  float* bias_pg         = (float*)alloc(256 * 4);
  float* bias_gs         = (float*)alloc(2048 * 4);
  char* U                = (char*)alloc((size_t)12 * 1024 * 1024);
  float* tmp_pg          = (float*)U;                           // [T][256] f32, 8 MB
  float* gated           = (float*)(U + 8 * 1024 * 1024);       // [T][128] f32, 4 MB
  float2* carryA         = (float2*)alloc((size_t)NSEG * 4096 * 8);                // 4 MB
  float2* carryB         = (float2*)alloc((size_t)NSEG * 4096 * 8);                // 4 MB
  unsigned short* st_bf  = (unsigned short*)alloc((size_t)CHUNK * 8192 * 2);       // 32 MB
  float* partials        = (float*)alloc((size_t)KS * CHUNK * 1024 * 4);           // 32 MB
  unsigned short* gs_o   = st_bf;   // [T][2048] bf16, 32 MB — reuses st_bf after chunk loop
  (void)ws_size; (void)n_in; (void)in_sizes;

  dim3 blk(256);
  long nx = (long)T_DIM * IN_DIM;
  f2bf_kernel<<<(unsigned)((nx + 255) / 256), blk, 0, stream>>>(x, x_bf, nx);
  permconv_kernel<<<32768, blk, 0, stream>>>(mix_w, Bmix, 8388608L);
  f2bf_kernel<<<4096, blk, 0, stream>>>(gout_w, Wgs, 1048576L);
  f2bf_kernel<<<4096, blk, 0, stream>>>(skip_w, Wgs + 1048576, 1048576L);
  f2bf_kernel<<<512, blk, 0, stream>>>(pre_w, Wpg, 131072L);
  f2bf_kernel<<<512, blk, 0, stream>>>(gin_w, Wpg + 131072, 131072L);
  concat2_kernel<<<1, 256, 0, stream>>>(pre_b, 128, gin_b, 128, bias_pg);
  concat2_kernel<<<8, 256, 0, stream>>>(gout_b, 1024, skip_b, 1024, bias_gs);

  // gated_x path
  gemm_bf16_kernel<<<dim3(2, 64), blk, 0, stream>>>(x_bf, Wpg, bias_pg, tmp_pg,
                                                    256, IN_DIM, 0);
  gated_kernel<<<(T_DIM * M_DIM) / 256, blk, 0, stream>>>(tmp_pg, gated);

  // parallel scan P1/P2
  scan_p1_kernel<<<NSEG * 16, blk, 0, stream>>>(gated, done, a, b, carryA, carryB);
  scan_p2_kernel<<<16, blk, 0, stream>>>(carryA, carryB, s0_re, s0_im);

  // per chunk: P3 -> split-K mix GEMM -> reduce
  for (int ch = 0; ch < NCH; ++ch) {
    int tbase = ch * CHUNK;
    scan_p3_kernel<<<(CHUNK / SEG) * 16, blk, 0, stream>>>(gated, done, a, b, carryB,
                                                           states_f, pair_mode,
                                                           (unsigned int*)st_bf, tbase,
                                                           CHUNK / SEG);
    gemm_splitk_kernel<<<8 * (CHUNK / 128) * KS, blk, 0, stream>>>(st_bf, Bmix, partials);
    reduce_kernel<<<CHUNK, blk, 0, stream>>>((const f32x4*)partials, (const f32x4*)mix_b,
                                             (f32x4*)(out_f + (size_t)tbase * OUT_DIM));
  }

  // merged gout+skip GEMM: raw logits bf16, sigmoid applied in LN
  gemm_bf16_kernel<<<dim3(16, 64), blk, 0, stream>>>(x_bf, Wgs, bias_gs, gs_o,
                                                     2048, IN_DIM, 2);

  // LN + gating epilogue
  ln_kernel<<<T_DIM, blk, 0, stream>>>(out_f, gs_o);
}

// Round 5
// 461.718 us; speedup vs baseline: 6.8060x; 1.1617x over previous
//
#include <hip/hip_runtime.h>
#include <stdint.h>

#define T_DIM 8192
#define IN_DIM 1024
#define OUT_DIM 1024
#define M_DIM 128
#define SEG 64
#define NSEG (T_DIM / SEG)   // 128
#define CHUNK 2048           // fallback path only
#define KS_FB 4

typedef __bf16 bf16x8 __attribute__((ext_vector_type(8)));
typedef float f32x4 __attribute__((ext_vector_type(4)));

__device__ inline unsigned short f2bf(float f) {
  unsigned int u = __float_as_uint(f);
  unsigned int r = (u + 0x7fffu + ((u >> 16) & 1u)) >> 16;
  return (unsigned short)r;
}
__device__ inline float bf2f(unsigned short h) {
  return __uint_as_float(((unsigned int)h) << 16);
}
__device__ inline float sigm(float v) { return 1.f / (1.f + expf(-v)); }

// ---------------- float -> bf16 elementwise ----------------
__global__ __launch_bounds__(256) void f2bf_kernel(const float* __restrict__ in,
                                                   unsigned short* __restrict__ out, long n) {
  long i = (long)blockIdx.x * 256 + threadIdx.x;
  if (i < n) out[i] = f2bf(in[i]);
}

// ---- mix_w column-permute + bf16: B[o][k] = bf16(mix_w[o][ (k>>6)*64 + (k&1)*32 + ((k>>1)&31) ])
__global__ __launch_bounds__(256) void permconv_kernel(const float* __restrict__ w,
                                                       unsigned short* __restrict__ o, long n) {
  long i = (long)blockIdx.x * 256 + threadIdx.x;
  if (i >= n) return;
  long row = i >> 13;
  int k = (int)(i & 8191);
  int src = ((k >> 6) << 6) | ((k & 1) << 5) | ((k >> 1) & 31);
  o[i] = f2bf(w[(row << 13) + src]);
}

// ---- Wgs bf16 [2304][1024] = rows: gout(0..1023) skip(1024..2047) pre(2048..2175) gin(2176..2303)
__global__ __launch_bounds__(256) void wcat_kernel(const float* __restrict__ gout_w,
                                                   const float* __restrict__ skip_w,
                                                   const float* __restrict__ pre_w,
                                                   const float* __restrict__ gin_w,
                                                   unsigned short* __restrict__ o) {
  long i = (long)blockIdx.x * 256 + threadIdx.x;   // < 2304*1024
  if (i >= (long)2304 * 1024) return;
  int row = (int)(i >> 10), col = (int)(i & 1023);
  float v;
  if (row < 1024)       v = gout_w[row * 1024 + col];
  else if (row < 2048)  v = skip_w[(row - 1024) * 1024 + col];
  else if (row < 2176)  v = pre_w[(row - 2048) * 1024 + col];
  else                  v = gin_w[(row - 2176) * 1024 + col];
  o[i] = f2bf(v);
}

__global__ void bcat_kernel(const float* __restrict__ gout_b, const float* __restrict__ skip_b,
                            const float* __restrict__ pre_b, const float* __restrict__ gin_b,
                            float* __restrict__ dst) {
  int i = blockIdx.x * 256 + threadIdx.x;
  if (i >= 2304) return;
  float v;
  if (i < 1024)      v = gout_b[i];
  else if (i < 2048) v = skip_b[i - 1024];
  else if (i < 2176) v = pre_b[i - 2048];
  else               v = gin_b[i - 2176];
  dst[i] = v;
}

// ---- gamma tables: gam = exp(-|a|+ib), gamL = gam^SEG (double precision once) ----
__global__ void gamma_kernel(const float* __restrict__ a, const float* __restrict__ b,
                             float2* __restrict__ gam, float2* __restrict__ gamL) {
  int tid = blockIdx.x * 256 + threadIdx.x;   // 0..4095
  int m = tid >> 5, c = tid & 31;
  double aa = fabs((double)a[m]);
  double ang = (double)b[c];
  double mag = exp(-aa);
  gam[tid] = make_float2((float)(mag * cos(ang)), (float)(mag * sin(ang)));
  double magL = exp(-aa * (double)SEG);
  double angL = ang * (double)SEG;
  gamL[tid] = make_float2((float)(magL * cos(angL)), (float)(magL * sin(angL)));
}

// ---------------- merged gout/skip/pre/gin GEMM ----------------
// A [T][1024] bf16, B=Wgs [2304][1024] bf16. cols<2048 -> bf16 logits gs[T][2048];
// cols>=2048 -> f32 tmp[T][256]. grid (18, 64), block 256.
__global__ __launch_bounds__(256) void gemm_gs_kernel(
    const unsigned short* __restrict__ A, const unsigned short* __restrict__ B,
    const float* __restrict__ bias, unsigned short* __restrict__ gs,
    float* __restrict__ tmp) {
  __shared__ __align__(16) unsigned short As[128 * 64];
  __shared__ __align__(16) unsigned short Bs[128 * 64];
  const int n0 = blockIdx.x * 128, t0 = blockIdx.y * 128;
  const int tid = threadIdx.x;
  const int lane = tid & 63, w = tid >> 6;
  const int wr = w >> 1, wc = w & 1;

  f32x4 acc[4][4] = {};
  const int srow = tid >> 3;
  const int skk = (tid & 7) * 8;
  const unsigned short* Ab = A + (size_t)(t0 + srow) * 1024 + skk;
  const unsigned short* Bb = B + (size_t)(n0 + srow) * 1024 + skk;

  for (int k0 = 0; k0 < 1024; k0 += 64) {
#pragma unroll
    for (int cc = 0; cc < 4; ++cc) {
      __builtin_amdgcn_global_load_lds(
          (const __attribute__((address_space(1))) void*)(Ab + k0 + (size_t)cc * 32 * 1024),
          (__attribute__((address_space(3))) void*)(As + cc * 2048 + w * 512), 16, 0, 0);
      __builtin_amdgcn_global_load_lds(
          (const __attribute__((address_space(1))) void*)(Bb + k0 + (size_t)cc * 32 * 1024),
          (__attribute__((address_space(3))) void*)(Bs + cc * 2048 + w * 512), 16, 0, 0);
    }
    __syncthreads();
    const int krd = (lane >> 4) * 8;
#pragma unroll
    for (int kk = 0; kk < 64; kk += 32) {
      bf16x8 af[4], bfr[4];
#pragma unroll
      for (int i = 0; i < 4; ++i) {
        af[i]  = *(const bf16x8*)&As[(wr * 64 + i * 16 + (lane & 15)) * 64 + kk + krd];
        bfr[i] = *(const bf16x8*)&Bs[(wc * 64 + i * 16 + (lane & 15)) * 64 + kk + krd];
      }
#pragma unroll
      for (int i = 0; i < 4; ++i)
#pragma unroll
        for (int j = 0; j < 4; ++j)
          acc[i][j] = __builtin_amdgcn_mfma_f32_16x16x32_bf16(af[i], bfr[j], acc[i][j], 0, 0, 0);
    }
    __syncthreads();
  }

  const int rbase = t0 + wr * 64 + ((lane >> 4) * 4);
  const int cbase = n0 + wc * 64 + (lane & 15);
#pragma unroll
  for (int j = 0; j < 4; ++j) {
    const int col = cbase + j * 16;
    const float bv = bias[col];
#pragma unroll
    for (int i = 0; i < 4; ++i) {
#pragma unroll
      for (int r = 0; r < 4; ++r) {
        float v = acc[i][j][r] + bv;
        int row = rbase + i * 16 + r;
        if (col < 2048) gs[(size_t)row * 2048 + col] = f2bf(v);
        else            tmp[(size_t)row * 256 + (col - 2048)] = v;
      }
    }
  }
}

// ---------------- split-K mix GEMM: partials[ks][prows][1024] ----------------
// A [prows_total][8192] bf16, B [1024][8192] bf16.
// flat grid = 8 * nbm * KS, XCD-swizzled; bm-major within XCD for B L2-residency.
__global__ __launch_bounds__(256) void gemm_splitk_kernel(
    const unsigned short* __restrict__ A, const unsigned short* __restrict__ B,
    float* __restrict__ partials, int nbm, int kslice, int prows) {
  __shared__ __align__(16) unsigned short As[128 * 64];
  __shared__ __align__(16) unsigned short Bs[128 * 64];
  const int bfl = blockIdx.x;
  const int cpx = gridDim.x >> 3;
  const int wid = (bfl & 7) * cpx + (bfl >> 3);   // bijective (nwg % 8 == 0)
  const int bm = wid % nbm;
  const int bn = (wid / nbm) & 7;
  const int ks = wid / (nbm * 8);
  const int n0 = bn * 128, t0 = bm * 128;
  const int tid = threadIdx.x;
  const int lane = tid & 63, w = tid >> 6;
  const int wr = w >> 1, wc = w & 1;

  f32x4 acc[4][4] = {};
  const int srow = tid >> 3;
  const int skk = (tid & 7) * 8;
  const unsigned short* Ab = A + (size_t)(t0 + srow) * 8192 + ks * kslice + skk;
  const unsigned short* Bb = B + (size_t)(n0 + srow) * 8192 + ks * kslice + skk;

  for (int k0 = 0; k0 < kslice; k0 += 64) {
#pragma unroll
    for (int cc = 0; cc < 4; ++cc) {
      __builtin_amdgcn_global_load_lds(
          (const __attribute__((address_space(1))) void*)(Ab + k0 + (size_t)cc * 32 * 8192),
          (__attribute__((address_space(3))) void*)(As + cc * 2048 + w * 512), 16, 0, 0);
      __builtin_amdgcn_global_load_lds(
          (const __attribute__((address_space(1))) void*)(Bb + k0 + (size_t)cc * 32 * 8192),
          (__attribute__((address_space(3))) void*)(Bs + cc * 2048 + w * 512), 16, 0, 0);
    }
    __syncthreads();
    const int krd = (lane >> 4) * 8;
#pragma unroll
    for (int kk = 0; kk < 64; kk += 32) {
      bf16x8 af[4], bfr[4];
#pragma unroll
      for (int i = 0; i < 4; ++i) {
        af[i]  = *(const bf16x8*)&As[(wr * 64 + i * 16 + (lane & 15)) * 64 + kk + krd];
        bfr[i] = *(const bf16x8*)&Bs[(wc * 64 + i * 16 + (lane & 15)) * 64 + kk + krd];
      }
#pragma unroll
      for (int i = 0; i < 4; ++i)
#pragma unroll
        for (int j = 0; j < 4; ++j)
          acc[i][j] = __builtin_amdgcn_mfma_f32_16x16x32_bf16(af[i], bfr[j], acc[i][j], 0, 0, 0);
    }
    __syncthreads();
  }

  float* Cp = partials + (size_t)ks * prows * 1024;
  const int rbase = t0 + wr * 64 + ((lane >> 4) * 4);
  const int cbase = n0 + wc * 64 + (lane & 15);
#pragma unroll
  for (int j = 0; j < 4; ++j) {
    const int col = cbase + j * 16;
#pragma unroll
    for (int i = 0; i < 4; ++i)
#pragma unroll
      for (int r = 0; r < 4; ++r)
        Cp[(size_t)(rbase + i * 16 + r) * 1024 + col] = acc[i][j][r];
  }
}

// fallback reduce: KS_FB partial slabs + bias -> out chunk
__global__ __launch_bounds__(256) void reduce_kernel(const f32x4* __restrict__ partials,
                                                     const f32x4* __restrict__ bias4,
                                                     f32x4* __restrict__ outc) {
  int i = blockIdx.x * 256 + threadIdx.x;
  const size_t stride = (size_t)CHUNK * 256;
  f32x4 s = partials[i];
#pragma unroll
  for (int p = 1; p < KS_FB; ++p) s += partials[(size_t)p * stride + i];
  s += bias4[i & 255];
  outc[i] = s;
}

// ---------------- gated_x = pre * sigmoid(gin) ----------------
__global__ __launch_bounds__(256) void gated_kernel(const float* __restrict__ tmp,
                                                    float* __restrict__ gated) {
  int i = blockIdx.x * 256 + threadIdx.x;
  int t = i >> 7, m = i & 127;
  float p = tmp[t * 256 + m];
  float g = tmp[t * 256 + 128 + m];
  gated[i] = p * sigm(g);
}

// ================= parallel scan =================
__global__ __launch_bounds__(256) void scan_p1_kernel(
    const float* __restrict__ gated, const int* __restrict__ done,
    const float2* __restrict__ gam, const float2* __restrict__ gamL,
    float2* __restrict__ carryA, float2* __restrict__ carryB) {
  int gid = blockIdx.x * 256 + threadIdx.x;
  int seg = gid >> 12, tid = gid & 4095;
  int m = tid >> 5;
  float2 g = gam[tid];
  int t0 = seg * SEG;
  float sr = 0.f, si = 0.f, keep_all = 1.f;
  for (int tt = 0; tt < SEG; ++tt) {
    int t = t0 + tt;
    float xv = gated[t * M_DIM + m];
    bool d = done[t] != 0;
    float pr = d ? 0.f : sr;
    float pi = d ? 0.f : si;
    if (d) keep_all = 0.f;
    sr = fmaf(g.x, pr, fmaf(-g.y, pi, xv));
    si = fmaf(g.y, pr, g.x * pi);
  }
  carryB[(size_t)seg * 4096 + tid] = make_float2(sr, si);
  float2 gL = gamL[tid];
  carryA[(size_t)seg * 4096 + tid] = make_float2(keep_all * gL.x, keep_all * gL.y);
}

__global__ __launch_bounds__(256) void scan_p2_kernel(
    const float2* __restrict__ carryA, float2* __restrict__ carryB,
    const float* __restrict__ s0_re, const float* __restrict__ s0_im) {
  int tid = blockIdx.x * 256 + threadIdx.x;
  float sr = s0_re[tid], si = s0_im[tid];
  for (int p = 0; p < NSEG; ++p) {
    size_t idx = (size_t)p * 4096 + tid;
    float2 A = carryA[idx];
    float2 B = carryB[idx];
    carryB[idx] = make_float2(sr, si);
    float nr = fmaf(A.x, sr, fmaf(-A.y, si, B.x));
    float ni = fmaf(A.y, sr, fmaf(A.x, si, B.y));
    sr = nr; si = ni;
  }
}

__global__ __launch_bounds__(256) void scan_p3_kernel(
    const float* __restrict__ gated, const int* __restrict__ done,
    const float2* __restrict__ gam, const float2* __restrict__ segstart,
    float* __restrict__ out_states, int pair_mode,
    unsigned int* __restrict__ st_bf, int tbase) {
  int gid = blockIdx.x * 256 + threadIdx.x;
  int segl = gid >> 12, tid = gid & 4095;
  int m = tid >> 5;
  int seg = tbase / SEG + segl;
  float2 g = gam[tid];
  float2 s = segstart[(size_t)seg * 4096 + tid];
  float sr = s.x, si = s.y;
  int t0 = seg * SEG;
  for (int tt = 0; tt < SEG; ++tt) {
    int t = t0 + tt;
    float xv = gated[t * M_DIM + m];
    bool d = done[t] != 0;
    float pr = d ? 0.f : sr;
    float pi = d ? 0.f : si;
    sr = fmaf(g.x, pr, fmaf(-g.y, pi, xv));
    si = fmaf(g.y, pr, g.x * pi);
    if (pair_mode) {
      ((float2*)out_states)[(size_t)t * 4096 + tid] = make_float2(sr, si);
    } else {
      out_states[(size_t)t * 4096 + tid] = sr;
    }
    st_bf[(size_t)(t - tbase) * 4096 + tid] =
        (unsigned int)f2bf(sr) | ((unsigned int)f2bf(si) << 16);
  }
}

// ---------------- fused reduce + bias + LN + gates ----------------
// nred>=1: z = sum of nred partial slabs (stride T*1024) + mix_b.  nred==0: z = out (prereduced).
__global__ __launch_bounds__(256) void ln_kernel(const float* __restrict__ partials, int nred,
                                                 const float* __restrict__ mixb,
                                                 const unsigned short* __restrict__ gs,
                                                 float* __restrict__ out) {
  const int t = blockIdx.x;
  const int tid = threadIdx.x;
  __shared__ float sm[8];
  const int o = tid * 4;
  f32x4 z;
  if (nred == 0) {
    z = *(const f32x4*)&out[(size_t)t * 1024 + o];
  } else {
    z = *(const f32x4*)&partials[(size_t)t * 1024 + o];
    for (int p = 1; p < nred; ++p)
      z += *(const f32x4*)&partials[(size_t)p * T_DIM * 1024 + (size_t)t * 1024 + o];
    z += *(const f32x4*)&mixb[o];
  }
  ushort4 gu = *(const ushort4*)&gs[(size_t)t * 2048 + o];
  ushort4 su = *(const ushort4*)&gs[(size_t)t * 2048 + 1024 + o];
  float g[4], sk[4], zg[4];
  g[0] = sigm(bf2f(gu.x)); g[1] = sigm(bf2f(gu.y));
  g[2] = sigm(bf2f(gu.z)); g[3] = sigm(bf2f(gu.w));
  sk[0] = bf2f(su.x); sk[1] = bf2f(su.y); sk[2] = bf2f(su.z); sk[3] = bf2f(su.w);
  float sum = 0.f;
#pragma unroll
  for (int j = 0; j < 4; ++j) { zg[j] = z[j] * g[j]; sum += zg[j]; }
#pragma unroll
  for (int off = 32; off > 0; off >>= 1) sum += __shfl_down(sum, off, 64);
  if ((tid & 63) == 0) sm[tid >> 6] = sum;
  __syncthreads();
  const float mu = (sm[0] + sm[1] + sm[2] + sm[3]) * (1.f / 1024.f);
  float sq = 0.f;
#pragma unroll
  for (int j = 0; j < 4; ++j) { float d = zg[j] - mu; sq += d * d; }
#pragma unroll
  for (int off = 32; off > 0; off >>= 1) sq += __shfl_down(sq, off, 64);
  if ((tid & 63) == 0) sm[4 + (tid >> 6)] = sq;
  __syncthreads();
  const float var = (sm[4] + sm[5] + sm[6] + sm[7]) * (1.f / 1024.f);
  const float rstd = 1.f / sqrtf(var + 1e-5f);
  f32x4 res;
#pragma unroll
  for (int j = 0; j < 4; ++j) res[j] = (zg[j] - mu) * rstd + sk[j] * (1.f - g[j]);
  *(f32x4*)&out[(size_t)t * 1024 + o] = res;
}

extern "C" void kernel_launch(void* const* d_in, const int* in_sizes, int n_in,
                              void* d_out, int out_size, void* d_ws, size_t ws_size,
                              hipStream_t stream) {
  const float* x      = (const float*)d_in[0];
  const int*   done   = (const int*)d_in[1];
  const float* s0_re  = (const float*)d_in[2];
  const float* s0_im  = (const float*)d_in[3];
  const float* a      = (const float*)d_in[4];
  const float* b      = (const float*)d_in[5];
  const float* pre_w  = (const float*)d_in[6];
  const float* pre_b  = (const float*)d_in[7];
  const float* gin_w  = (const float*)d_in[8];
  const float* gin_b  = (const float*)d_in[9];
  const float* gout_w = (const float*)d_in[10];
  const float* gout_b = (const float*)d_in[11];
  const float* skip_w = (const float*)d_in[12];
  const float* skip_b = (const float*)d_in[13];
  const float* mix_w  = (const float*)d_in[14];
  const float* mix_b  = (const float*)d_in[15];

  float* out_f = (float*)d_out;                               // [T][1024]
  float* states_f = out_f + (size_t)T_DIM * OUT_DIM;
  const int pair_mode = (out_size >= 75000000) ? 1 : 0;

  char* ws = (char*)d_ws;
  size_t off = 0;
  auto alloc = [&](size_t bytes) {
    void* p = ws + off;
    off = (off + bytes + 255) & ~(size_t)255;
    return p;
  };
  unsigned short* x_bf   = (unsigned short*)alloc((size_t)T_DIM * IN_DIM * 2);     // 16.8 MB
  unsigned short* Bmix   = (unsigned short*)alloc((size_t)OUT_DIM * 8192 * 2);     // 16.8 MB
  unsigned short* Wgs    = (unsigned short*)alloc((size_t)2304 * IN_DIM * 2);      // 4.7 MB
  float* bias_gs         = (float*)alloc(2304 * 4);
  float* tmp_pg          = (float*)alloc((size_t)T_DIM * 256 * 4);                 // 8.4 MB
  float* gated           = (float*)alloc((size_t)T_DIM * M_DIM * 4);               // 4.2 MB
  float2* gam            = (float2*)alloc(4096 * 8);
  float2* gamL           = (float2*)alloc(4096 * 8);
  float2* carryA         = (float2*)alloc((size_t)NSEG * 4096 * 8);                // 4.2 MB
  float2* carryB         = (float2*)alloc((size_t)NSEG * 4096 * 8);                // 4.2 MB
  unsigned short* gs_o   = (unsigned short*)alloc((size_t)T_DIM * 2048 * 2);       // 33.6 MB

  // main path needs st_bf full-T (134 MB) + partials 2 slabs (67 MB)
  size_t need_main = off + (size_t)T_DIM * 8192 * 2 + (size_t)2 * T_DIM * 1024 * 4 + 1024;
  const int full_path = (ws_size == 0 || ws_size >= need_main) ? 1 : 0;

  dim3 blk(256);
  long nx = (long)T_DIM * IN_DIM;
  f2bf_kernel<<<(unsigned)((nx + 255) / 256), blk, 0, stream>>>(x, x_bf, nx);
  permconv_kernel<<<32768, blk, 0, stream>>>(mix_w, Bmix, 8388608L);
  wcat_kernel<<<9216, blk, 0, stream>>>(gout_w, skip_w, pre_w, gin_w, Wgs);
  bcat_kernel<<<9, blk, 0, stream>>>(gout_b, skip_b, pre_b, gin_b, bias_gs);
  gamma_kernel<<<16, blk, 0, stream>>>(a, b, gam, gamL);

  // merged gout/skip/pre/gin GEMM
  gemm_gs_kernel<<<dim3(18, 64), blk, 0, stream>>>(x_bf, Wgs, bias_gs, gs_o, tmp_pg);
  gated_kernel<<<(T_DIM * M_DIM) / 256, blk, 0, stream>>>(tmp_pg, gated);

  // parallel scan P1/P2
  scan_p1_kernel<<<NSEG * 16, blk, 0, stream>>>(gated, done, gam, gamL, carryA, carryB);
  scan_p2_kernel<<<16, blk, 0, stream>>>(carryA, carryB, s0_re, s0_im);

  if (full_path) {
    unsigned short* st_bf = (unsigned short*)alloc((size_t)T_DIM * 8192 * 2);      // 134 MB
    float* partials       = (float*)alloc((size_t)2 * T_DIM * 1024 * 4);           // 67 MB
    // P3 full-T, then ONE split-K GEMM (8 bn x 64 bm x 2 ks = 1024 blocks, 4/CU)
    scan_p3_kernel<<<NSEG * 16, blk, 0, stream>>>(gated, done, gam, carryB,
                                                  states_f, pair_mode,
                                                  (unsigned int*)st_bf, 0);
    gemm_splitk_kernel<<<1024, blk, 0, stream>>>(st_bf, Bmix, partials,
                                                 64, 4096, T_DIM);
    // fused reduce(2) + bias + LN + gates
    ln_kernel<<<T_DIM, blk, 0, stream>>>(partials, 2, mix_b, gs_o, out_f);
  } else {
    unsigned short* st_bf = (unsigned short*)alloc((size_t)CHUNK * 8192 * 2);      // 32 MB
    float* partials       = (float*)alloc((size_t)KS_FB * CHUNK * 1024 * 4);       // 32 MB
    for (int ch = 0; ch < T_DIM / CHUNK; ++ch) {
      int tbase = ch * CHUNK;
      scan_p3_kernel<<<(CHUNK / SEG) * 16, blk, 0, stream>>>(gated, done, gam, carryB,
                                                             states_f, pair_mode,
                                                             (unsigned int*)st_bf, tbase);
      gemm_splitk_kernel<<<8 * (CHUNK / 128) * KS_FB, blk, 0, stream>>>(
          st_bf, Bmix, partials, CHUNK / 128, 8192 / KS_FB, CHUNK);
      reduce_kernel<<<CHUNK, blk, 0, stream>>>((const f32x4*)partials, (const f32x4*)mix_b,
                                               (f32x4*)(out_f + (size_t)tbase * OUT_DIM));
    }
    ln_kernel<<<T_DIM, blk, 0, stream>>>(nullptr, 0, mix_b, gs_o, out_f);
  }
  (void)n_in; (void)in_sizes;
}

// Round 6
// 419.837 us; speedup vs baseline: 7.4849x; 1.0998x over previous
//
#include <hip/hip_runtime.h>
#include <stdint.h>

#define T_DIM 8192
#define IN_DIM 1024
#define OUT_DIM 1024
#define M_DIM 128
#define SEG 64
#define NSEG (T_DIM / SEG)   // 128
#define CHUNK 2048           // fallback path only
#define KS_FB 4

typedef __bf16 bf16x8 __attribute__((ext_vector_type(8)));
typedef float f32x4 __attribute__((ext_vector_type(4)));

__device__ inline unsigned short f2bf(float f) {
  unsigned int u = __float_as_uint(f);
  unsigned int r = (u + 0x7fffu + ((u >> 16) & 1u)) >> 16;
  return (unsigned short)r;
}
__device__ inline float bf2f(unsigned short h) {
  return __uint_as_float(((unsigned int)h) << 16);
}
__device__ inline float sigm(float v) { return 1.f / (1.f + expf(-v)); }

// ---------------- float -> bf16 elementwise ----------------
__global__ __launch_bounds__(256) void f2bf_kernel(const float* __restrict__ in,
                                                   unsigned short* __restrict__ out, long n) {
  long i = (long)blockIdx.x * 256 + threadIdx.x;
  if (i < n) out[i] = f2bf(in[i]);
}

// ---- mix_w column-permute + bf16: B[o][k] = bf16(mix_w[o][ (k>>6)*64 + (k&1)*32 + ((k>>1)&31) ])
__global__ __launch_bounds__(256) void permconv_kernel(const float* __restrict__ w,
                                                       unsigned short* __restrict__ o, long n) {
  long i = (long)blockIdx.x * 256 + threadIdx.x;
  if (i >= n) return;
  long row = i >> 13;
  int k = (int)(i & 8191);
  int src = ((k >> 6) << 6) | ((k & 1) << 5) | ((k >> 1) & 31);
  o[i] = f2bf(w[(row << 13) + src]);
}

// ---- Wgs bf16 [2304][1024] = rows: gout(0..1023) skip(1024..2047) pre(2048..2175) gin(2176..2303)
__global__ __launch_bounds__(256) void wcat_kernel(const float* __restrict__ gout_w,
                                                   const float* __restrict__ skip_w,
                                                   const float* __restrict__ pre_w,
                                                   const float* __restrict__ gin_w,
                                                   unsigned short* __restrict__ o) {
  long i = (long)blockIdx.x * 256 + threadIdx.x;   // < 2304*1024
  if (i >= (long)2304 * 1024) return;
  int row = (int)(i >> 10), col = (int)(i & 1023);
  float v;
  if (row < 1024)       v = gout_w[row * 1024 + col];
  else if (row < 2048)  v = skip_w[(row - 1024) * 1024 + col];
  else if (row < 2176)  v = pre_w[(row - 2048) * 1024 + col];
  else                  v = gin_w[(row - 2176) * 1024 + col];
  o[i] = f2bf(v);
}

__global__ void bcat_kernel(const float* __restrict__ gout_b, const float* __restrict__ skip_b,
                            const float* __restrict__ pre_b, const float* __restrict__ gin_b,
                            float* __restrict__ dst) {
  int i = blockIdx.x * 256 + threadIdx.x;
  if (i >= 2304) return;
  float v;
  if (i < 1024)      v = gout_b[i];
  else if (i < 2048) v = skip_b[i - 1024];
  else if (i < 2176) v = pre_b[i - 2048];
  else               v = gin_b[i - 2176];
  dst[i] = v;
}

// ---- gamma tables: gam = exp(-|a|+ib), gamL = gam^SEG (double precision once) ----
__global__ void gamma_kernel(const float* __restrict__ a, const float* __restrict__ b,
                             float2* __restrict__ gam, float2* __restrict__ gamL) {
  int tid = blockIdx.x * 256 + threadIdx.x;   // 0..4095
  int m = tid >> 5, c = tid & 31;
  double aa = fabs((double)a[m]);
  double ang = (double)b[c];
  double mag = exp(-aa);
  gam[tid] = make_float2((float)(mag * cos(ang)), (float)(mag * sin(ang)));
  double magL = exp(-aa * (double)SEG);
  double angL = ang * (double)SEG;
  gamL[tid] = make_float2((float)(magL * cos(angL)), (float)(magL * sin(angL)));
}

// ======== shared GEMM tile body (T2 swizzle, m97 staging) ========
// LDS layout: linear [128 rows][64 cols] bf16 per operand, 32-row subtiles.
// Staging: global source chunk XOR'd by (srow&7); reader XORs (lane&7)<<3.

// ---------------- merged gout/skip/pre/gin GEMM ----------------
// A [T][1024] bf16, B=Wgs [2304][1024] bf16. cols<2048 -> bf16 logits gs[T][2048];
// cols>=2048 -> f32 tmp[T][256]. flat grid 1152 (XCD-partitioned), block 256.
__global__ __launch_bounds__(256) void gemm_gs_kernel(
    const unsigned short* __restrict__ A, const unsigned short* __restrict__ B,
    const float* __restrict__ bias, unsigned short* __restrict__ gs,
    float* __restrict__ tmp) {
  __shared__ __align__(16) unsigned short As[128 * 64];
  __shared__ __align__(16) unsigned short Bs[128 * 64];
  // XCD-partitioned decomposition: 1152 blocks, 144 per XCD, 8-bm slice each
  const int xcd = blockIdx.x & 7;
  const int idx = blockIdx.x >> 3;        // 0..143
  const int bn = idx % 18;
  const int bm = xcd * 8 + idx / 18;
  const int n0 = bn * 128, t0 = bm * 128;
  const int tid = threadIdx.x;
  const int lane = tid & 63, w = tid >> 6;
  const int wr = w >> 1, wc = w & 1;

  f32x4 acc[4][4] = {};
  const int srow = tid >> 3;
  const int ksw = ((tid & 7) ^ (srow & 7)) * 8;     // swizzled source chunk
  const unsigned short* Ab = A + (size_t)(t0 + srow) * 1024 + ksw;
  const unsigned short* Bb = B + (size_t)(n0 + srow) * 1024 + ksw;

  for (int k0 = 0; k0 < 1024; k0 += 64) {
#pragma unroll
    for (int cc = 0; cc < 4; ++cc) {
      __builtin_amdgcn_global_load_lds(
          (const __attribute__((address_space(1))) void*)(Ab + k0 + (size_t)cc * 32 * 1024),
          (__attribute__((address_space(3))) void*)(As + cc * 2048 + w * 512), 16, 0, 0);
      __builtin_amdgcn_global_load_lds(
          (const __attribute__((address_space(1))) void*)(Bb + k0 + (size_t)cc * 32 * 1024),
          (__attribute__((address_space(3))) void*)(Bs + cc * 2048 + w * 512), 16, 0, 0);
    }
    __syncthreads();
    const int krd = (lane >> 4) * 8;
    const int rsw = (lane & 7) << 3;                 // reader XOR (row&7)<<3 elements
#pragma unroll
    for (int kk = 0; kk < 64; kk += 32) {
      bf16x8 af[4], bfr[4];
#pragma unroll
      for (int i = 0; i < 4; ++i) {
        af[i]  = *(const bf16x8*)&As[(wr * 64 + i * 16 + (lane & 15)) * 64 + ((kk + krd) ^ rsw)];
        bfr[i] = *(const bf16x8*)&Bs[(wc * 64 + i * 16 + (lane & 15)) * 64 + ((kk + krd) ^ rsw)];
      }
#pragma unroll
      for (int i = 0; i < 4; ++i)
#pragma unroll
        for (int j = 0; j < 4; ++j)
          acc[i][j] = __builtin_amdgcn_mfma_f32_16x16x32_bf16(af[i], bfr[j], acc[i][j], 0, 0, 0);
    }
    __syncthreads();
  }

  const int rbase = t0 + wr * 64 + ((lane >> 4) * 4);
  const int cbase = n0 + wc * 64 + (lane & 15);
#pragma unroll
  for (int j = 0; j < 4; ++j) {
    const int col = cbase + j * 16;
    const float bv = bias[col];
#pragma unroll
    for (int i = 0; i < 4; ++i) {
#pragma unroll
      for (int r = 0; r < 4; ++r) {
        float v = acc[i][j][r] + bv;
        int row = rbase + i * 16 + r;
        if (col < 2048) gs[(size_t)row * 2048 + col] = f2bf(v);
        else            tmp[(size_t)row * 256 + (col - 2048)] = v;
      }
    }
  }
}

// ---------------- split-K mix GEMM: partials[ks][prows][1024] ----------------
// A [prows][8192] bf16, B [1024][8192] bf16.
// xcd_map=1 (full path, 1024 blocks): each XCD owns {ks=xcd>>2, 16-bm slice, all 8 bn}.
// xcd_map=0 (fallback): old bijective swizzle.
__global__ __launch_bounds__(256) void gemm_splitk_kernel(
    const unsigned short* __restrict__ A, const unsigned short* __restrict__ B,
    float* __restrict__ partials, int nbm, int kslice, int prows, int xcd_map) {
  __shared__ __align__(16) unsigned short As[128 * 64];
  __shared__ __align__(16) unsigned short Bs[128 * 64];
  int bm, bn, ks;
  if (xcd_map) {
    const int xcd = blockIdx.x & 7;
    const int idx = blockIdx.x >> 3;      // 0..127
    ks = xcd >> 2;
    bm = (xcd & 3) * 16 + (idx >> 3);
    bn = idx & 7;
  } else {
    const int cpx = gridDim.x >> 3;
    const int wid = (blockIdx.x & 7) * cpx + (blockIdx.x >> 3);
    bm = wid % nbm;
    bn = (wid / nbm) & 7;
    ks = wid / (nbm * 8);
  }
  const int n0 = bn * 128, t0 = bm * 128;
  const int tid = threadIdx.x;
  const int lane = tid & 63, w = tid >> 6;
  const int wr = w >> 1, wc = w & 1;

  f32x4 acc[4][4] = {};
  const int srow = tid >> 3;
  const int ksw = ((tid & 7) ^ (srow & 7)) * 8;
  const unsigned short* Ab = A + (size_t)(t0 + srow) * 8192 + ks * kslice + ksw;
  const unsigned short* Bb = B + (size_t)(n0 + srow) * 8192 + ks * kslice + ksw;

  for (int k0 = 0; k0 < kslice; k0 += 64) {
#pragma unroll
    for (int cc = 0; cc < 4; ++cc) {
      __builtin_amdgcn_global_load_lds(
          (const __attribute__((address_space(1))) void*)(Ab + k0 + (size_t)cc * 32 * 8192),
          (__attribute__((address_space(3))) void*)(As + cc * 2048 + w * 512), 16, 0, 0);
      __builtin_amdgcn_global_load_lds(
          (const __attribute__((address_space(1))) void*)(Bb + k0 + (size_t)cc * 32 * 8192),
          (__attribute__((address_space(3))) void*)(Bs + cc * 2048 + w * 512), 16, 0, 0);
    }
    __syncthreads();
    const int krd = (lane >> 4) * 8;
    const int rsw = (lane & 7) << 3;
#pragma unroll
    for (int kk = 0; kk < 64; kk += 32) {
      bf16x8 af[4], bfr[4];
#pragma unroll
      for (int i = 0; i < 4; ++i) {
        af[i]  = *(const bf16x8*)&As[(wr * 64 + i * 16 + (lane & 15)) * 64 + ((kk + krd) ^ rsw)];
        bfr[i] = *(const bf16x8*)&Bs[(wc * 64 + i * 16 + (lane & 15)) * 64 + ((kk + krd) ^ rsw)];
      }
#pragma unroll
      for (int i = 0; i < 4; ++i)
#pragma unroll
        for (int j = 0; j < 4; ++j)
          acc[i][j] = __builtin_amdgcn_mfma_f32_16x16x32_bf16(af[i], bfr[j], acc[i][j], 0, 0, 0);
    }
    __syncthreads();
  }

  float* Cp = partials + (size_t)ks * prows * 1024;
  const int rbase = t0 + wr * 64 + ((lane >> 4) * 4);
  const int cbase = n0 + wc * 64 + (lane & 15);
#pragma unroll
  for (int j = 0; j < 4; ++j) {
    const int col = cbase + j * 16;
#pragma unroll
    for (int i = 0; i < 4; ++i)
#pragma unroll
      for (int r = 0; r < 4; ++r)
        Cp[(size_t)(rbase + i * 16 + r) * 1024 + col] = acc[i][j][r];
  }
}

// fallback reduce: KS_FB partial slabs + bias -> out chunk
__global__ __launch_bounds__(256) void reduce_kernel(const f32x4* __restrict__ partials,
                                                     const f32x4* __restrict__ bias4,
                                                     f32x4* __restrict__ outc) {
  int i = blockIdx.x * 256 + threadIdx.x;
  const size_t stride = (size_t)CHUNK * 256;
  f32x4 s = partials[i];
#pragma unroll
  for (int p = 1; p < KS_FB; ++p) s += partials[(size_t)p * stride + i];
  s += bias4[i & 255];
  outc[i] = s;
}

// ---------------- gated_x = pre * sigmoid(gin) ----------------
__global__ __launch_bounds__(256) void gated_kernel(const float* __restrict__ tmp,
                                                    float* __restrict__ gated) {
  int i = blockIdx.x * 256 + threadIdx.x;
  int t = i >> 7, m = i & 127;
  float p = tmp[t * 256 + m];
  float g = tmp[t * 256 + 128 + m];
  gated[i] = p * sigm(g);
}

// ================= parallel scan =================
__global__ __launch_bounds__(256) void scan_p1_kernel(
    const float* __restrict__ gated, const int* __restrict__ done,
    const float2* __restrict__ gam, const float2* __restrict__ gamL,
    float2* __restrict__ carryA, float2* __restrict__ carryB) {
  int gid = blockIdx.x * 256 + threadIdx.x;
  int seg = gid >> 12, tid = gid & 4095;
  int m = tid >> 5;
  float2 g = gam[tid];
  int t0 = seg * SEG;
  float sr = 0.f, si = 0.f, keep_all = 1.f;
  for (int tt = 0; tt < SEG; ++tt) {
    int t = t0 + tt;
    float xv = gated[t * M_DIM + m];
    bool d = done[t] != 0;
    float pr = d ? 0.f : sr;
    float pi = d ? 0.f : si;
    if (d) keep_all = 0.f;
    sr = fmaf(g.x, pr, fmaf(-g.y, pi, xv));
    si = fmaf(g.y, pr, g.x * pi);
  }
  carryB[(size_t)seg * 4096 + tid] = make_float2(sr, si);
  float2 gL = gamL[tid];
  carryA[(size_t)seg * 4096 + tid] = make_float2(keep_all * gL.x, keep_all * gL.y);
}

__global__ __launch_bounds__(256) void scan_p2_kernel(
    const float2* __restrict__ carryA, float2* __restrict__ carryB,
    const float* __restrict__ s0_re, const float* __restrict__ s0_im) {
  int tid = blockIdx.x * 256 + threadIdx.x;
  float sr = s0_re[tid], si = s0_im[tid];
  for (int p = 0; p < NSEG; ++p) {
    size_t idx = (size_t)p * 4096 + tid;
    float2 A = carryA[idx];
    float2 B = carryB[idx];
    carryB[idx] = make_float2(sr, si);
    float nr = fmaf(A.x, sr, fmaf(-A.y, si, B.x));
    float ni = fmaf(A.y, sr, fmaf(A.x, si, B.y));
    sr = nr; si = ni;
  }
}

__global__ __launch_bounds__(256) void scan_p3_kernel(
    const float* __restrict__ gated, const int* __restrict__ done,
    const float2* __restrict__ gam, const float2* __restrict__ segstart,
    float* __restrict__ out_states, int pair_mode,
    unsigned int* __restrict__ st_bf, int tbase) {
  int gid = blockIdx.x * 256 + threadIdx.x;
  int segl = gid >> 12, tid = gid & 4095;
  int m = tid >> 5;
  int seg = tbase / SEG + segl;
  float2 g = gam[tid];
  float2 s = segstart[(size_t)seg * 4096 + tid];
  float sr = s.x, si = s.y;
  int t0 = seg * SEG;
  for (int tt = 0; tt < SEG; ++tt) {
    int t = t0 + tt;
    float xv = gated[t * M_DIM + m];
    bool d = done[t] != 0;
    float pr = d ? 0.f : sr;
    float pi = d ? 0.f : si;
    sr = fmaf(g.x, pr, fmaf(-g.y, pi, xv));
    si = fmaf(g.y, pr, g.x * pi);
    if (pair_mode) {
      ((float2*)out_states)[(size_t)t * 4096 + tid] = make_float2(sr, si);
    } else {
      out_states[(size_t)t * 4096 + tid] = sr;
    }
    st_bf[(size_t)(t - tbase) * 4096 + tid] =
        (unsigned int)f2bf(sr) | ((unsigned int)f2bf(si) << 16);
  }
}

// ---------------- fused reduce + bias + LN + gates ----------------
__global__ __launch_bounds__(256) void ln_kernel(const float* __restrict__ partials, int nred,
                                                 const float* __restrict__ mixb,
                                                 const unsigned short* __restrict__ gs,
                                                 float* __restrict__ out) {
  const int t = blockIdx.x;
  const int tid = threadIdx.x;
  __shared__ float sm[8];
  const int o = tid * 4;
  f32x4 z;
  if (nred == 0) {
    z = *(const f32x4*)&out[(size_t)t * 1024 + o];
  } else {
    z = *(const f32x4*)&partials[(size_t)t * 1024 + o];
    for (int p = 1; p < nred; ++p)
      z += *(const f32x4*)&partials[(size_t)p * T_DIM * 1024 + (size_t)t * 1024 + o];
    z += *(const f32x4*)&mixb[o];
  }
  ushort4 gu = *(const ushort4*)&gs[(size_t)t * 2048 + o];
  ushort4 su = *(const ushort4*)&gs[(size_t)t * 2048 + 1024 + o];
  float g[4], sk[4], zg[4];
  g[0] = sigm(bf2f(gu.x)); g[1] = sigm(bf2f(gu.y));
  g[2] = sigm(bf2f(gu.z)); g[3] = sigm(bf2f(gu.w));
  sk[0] = bf2f(su.x); sk[1] = bf2f(su.y); sk[2] = bf2f(su.z); sk[3] = bf2f(su.w);
  float sum = 0.f;
#pragma unroll
  for (int j = 0; j < 4; ++j) { zg[j] = z[j] * g[j]; sum += zg[j]; }
#pragma unroll
  for (int off = 32; off > 0; off >>= 1) sum += __shfl_down(sum, off, 64);
  if ((tid & 63) == 0) sm[tid >> 6] = sum;
  __syncthreads();
  const float mu = (sm[0] + sm[1] + sm[2] + sm[3]) * (1.f / 1024.f);
  float sq = 0.f;
#pragma unroll
  for (int j = 0; j < 4; ++j) { float d = zg[j] - mu; sq += d * d; }
#pragma unroll
  for (int off = 32; off > 0; off >>= 1) sq += __shfl_down(sq, off, 64);
  if ((tid & 63) == 0) sm[4 + (tid >> 6)] = sq;
  __syncthreads();
  const float var = (sm[4] + sm[5] + sm[6] + sm[7]) * (1.f / 1024.f);
  const float rstd = 1.f / sqrtf(var + 1e-5f);
  f32x4 res;
#pragma unroll
  for (int j = 0; j < 4; ++j) res[j] = (zg[j] - mu) * rstd + sk[j] * (1.f - g[j]);
  *(f32x4*)&out[(size_t)t * 1024 + o] = res;
}

extern "C" void kernel_launch(void* const* d_in, const int* in_sizes, int n_in,
                              void* d_out, int out_size, void* d_ws, size_t ws_size,
                              hipStream_t stream) {
  const float* x      = (const float*)d_in[0];
  const int*   done   = (const int*)d_in[1];
  const float* s0_re  = (const float*)d_in[2];
  const float* s0_im  = (const float*)d_in[3];
  const float* a      = (const float*)d_in[4];
  const float* b      = (const float*)d_in[5];
  const float* pre_w  = (const float*)d_in[6];
  const float* pre_b  = (const float*)d_in[7];
  const float* gin_w  = (const float*)d_in[8];
  const float* gin_b  = (const float*)d_in[9];
  const float* gout_w = (const float*)d_in[10];
  const float* gout_b = (const float*)d_in[11];
  const float* skip_w = (const float*)d_in[12];
  const float* skip_b = (const float*)d_in[13];
  const float* mix_w  = (const float*)d_in[14];
  const float* mix_b  = (const float*)d_in[15];

  float* out_f = (float*)d_out;                               // [T][1024]
  float* states_f = out_f + (size_t)T_DIM * OUT_DIM;
  const int pair_mode = (out_size >= 75000000) ? 1 : 0;

  char* ws = (char*)d_ws;
  size_t off = 0;
  auto alloc = [&](size_t bytes) {
    void* p = ws + off;
    off = (off + bytes + 255) & ~(size_t)255;
    return p;
  };
  unsigned short* x_bf   = (unsigned short*)alloc((size_t)T_DIM * IN_DIM * 2);     // 16.8 MB
  unsigned short* Bmix   = (unsigned short*)alloc((size_t)OUT_DIM * 8192 * 2);     // 16.8 MB
  unsigned short* Wgs    = (unsigned short*)alloc((size_t)2304 * IN_DIM * 2);      // 4.7 MB
  float* bias_gs         = (float*)alloc(2304 * 4);
  float* tmp_pg          = (float*)alloc((size_t)T_DIM * 256 * 4);                 // 8.4 MB
  float* gated           = (float*)alloc((size_t)T_DIM * M_DIM * 4);               // 4.2 MB
  float2* gam            = (float2*)alloc(4096 * 8);
  float2* gamL           = (float2*)alloc(4096 * 8);
  float2* carryA         = (float2*)alloc((size_t)NSEG * 4096 * 8);                // 4.2 MB
  float2* carryB         = (float2*)alloc((size_t)NSEG * 4096 * 8);                // 4.2 MB
  unsigned short* gs_o   = (unsigned short*)alloc((size_t)T_DIM * 2048 * 2);       // 33.6 MB

  size_t need_main = off + (size_t)T_DIM * 8192 * 2 + (size_t)2 * T_DIM * 1024 * 4 + 1024;
  const int full_path = (ws_size == 0 || ws_size >= need_main) ? 1 : 0;

  dim3 blk(256);
  long nx = (long)T_DIM * IN_DIM;
  f2bf_kernel<<<(unsigned)((nx + 255) / 256), blk, 0, stream>>>(x, x_bf, nx);
  permconv_kernel<<<32768, blk, 0, stream>>>(mix_w, Bmix, 8388608L);
  wcat_kernel<<<9216, blk, 0, stream>>>(gout_w, skip_w, pre_w, gin_w, Wgs);
  bcat_kernel<<<9, blk, 0, stream>>>(gout_b, skip_b, pre_b, gin_b, bias_gs);
  gamma_kernel<<<16, blk, 0, stream>>>(a, b, gam, gamL);

  // merged gout/skip/pre/gin GEMM (flat 1152 blocks, XCD-partitioned)
  gemm_gs_kernel<<<1152, blk, 0, stream>>>(x_bf, Wgs, bias_gs, gs_o, tmp_pg);
  gated_kernel<<<(T_DIM * M_DIM) / 256, blk, 0, stream>>>(tmp_pg, gated);

  // parallel scan P1/P2
  scan_p1_kernel<<<NSEG * 16, blk, 0, stream>>>(gated, done, gam, gamL, carryA, carryB);
  scan_p2_kernel<<<16, blk, 0, stream>>>(carryA, carryB, s0_re, s0_im);

  if (full_path) {
    unsigned short* st_bf = (unsigned short*)alloc((size_t)T_DIM * 8192 * 2);      // 134 MB
    float* partials       = (float*)alloc((size_t)2 * T_DIM * 1024 * 4);           // 67 MB
    scan_p3_kernel<<<NSEG * 16, blk, 0, stream>>>(gated, done, gam, carryB,
                                                  states_f, pair_mode,
                                                  (unsigned int*)st_bf, 0);
    // ONE split-K GEMM: 1024 blocks, XCD-partitioned {ks, 16-bm slice, 8 bn}
    gemm_splitk_kernel<<<1024, blk, 0, stream>>>(st_bf, Bmix, partials,
                                                 64, 4096, T_DIM, 1);
    ln_kernel<<<T_DIM, blk, 0, stream>>>(partials, 2, mix_b, gs_o, out_f);
  } else {
    unsigned short* st_bf = (unsigned short*)alloc((size_t)CHUNK * 8192 * 2);      // 32 MB
    float* partials       = (float*)alloc((size_t)KS_FB * CHUNK * 1024 * 4);       // 32 MB
    for (int ch = 0; ch < T_DIM / CHUNK; ++ch) {
      int tbase = ch * CHUNK;
      scan_p3_kernel<<<(CHUNK / SEG) * 16, blk, 0, stream>>>(gated, done, gam, carryB,
                                                             states_f, pair_mode,
                                                             (unsigned int*)st_bf, tbase);
      gemm_splitk_kernel<<<8 * (CHUNK / 128) * KS_FB, blk, 0, stream>>>(
          st_bf, Bmix, partials, CHUNK / 128, 8192 / KS_FB, CHUNK, 0);
      reduce_kernel<<<CHUNK, blk, 0, stream>>>((const f32x4*)partials, (const f32x4*)mix_b,
                                               (f32x4*)(out_f + (size_t)tbase * OUT_DIM));
    }
    ln_kernel<<<T_DIM, blk, 0, stream>>>(nullptr, 0, mix_b, gs_o, out_f);
  }
  (void)n_in; (void)in_sizes;
}

// Round 7
// 370.402 us; speedup vs baseline: 8.4839x; 1.1335x over previous
//
#include <hip/hip_runtime.h>
#include <stdint.h>

#define T_DIM 8192
#define IN_DIM 1024
#define OUT_DIM 1024
#define M_DIM 128
#define SEG 64
#define NSEG (T_DIM / SEG)   // 128
#define CHUNK 2048           // fallback path only
#define KS_FB 4

typedef __bf16 bf16x8 __attribute__((ext_vector_type(8)));
typedef float f32x4 __attribute__((ext_vector_type(4)));

__device__ inline unsigned short f2bf(float f) {
  unsigned int u = __float_as_uint(f);
  unsigned int r = (u + 0x7fffu + ((u >> 16) & 1u)) >> 16;
  return (unsigned short)r;
}
__device__ inline float bf2f(unsigned short h) {
  return __uint_as_float(((unsigned int)h) << 16);
}
__device__ inline float sigm(float v) { return 1.f / (1.f + expf(-v)); }

// ---------------- float -> bf16 elementwise ----------------
__global__ __launch_bounds__(256) void f2bf_kernel(const float* __restrict__ in,
                                                   unsigned short* __restrict__ out, long n) {
  long i = (long)blockIdx.x * 256 + threadIdx.x;
  if (i < n) out[i] = f2bf(in[i]);
}

// ---- mix_w column-permute + bf16: B[o][k] = bf16(mix_w[o][ (k>>6)*64 + (k&1)*32 + ((k>>1)&31) ])
__global__ __launch_bounds__(256) void permconv_kernel(const float* __restrict__ w,
                                                       unsigned short* __restrict__ o, long n) {
  long i = (long)blockIdx.x * 256 + threadIdx.x;
  if (i >= n) return;
  long row = i >> 13;
  int k = (int)(i & 8191);
  int src = ((k >> 6) << 6) | ((k & 1) << 5) | ((k >> 1) & 31);
  o[i] = f2bf(w[(row << 13) + src]);
}

// ---- Wgs bf16 [2304][1024] = rows: gout(0..1023) skip(1024..2047) pre(2048..2175) gin(2176..2303)
__global__ __launch_bounds__(256) void wcat_kernel(const float* __restrict__ gout_w,
                                                   const float* __restrict__ skip_w,
                                                   const float* __restrict__ pre_w,
                                                   const float* __restrict__ gin_w,
                                                   unsigned short* __restrict__ o) {
  long i = (long)blockIdx.x * 256 + threadIdx.x;   // < 2304*1024
  if (i >= (long)2304 * 1024) return;
  int row = (int)(i >> 10), col = (int)(i & 1023);
  float v;
  if (row < 1024)       v = gout_w[row * 1024 + col];
  else if (row < 2048)  v = skip_w[(row - 1024) * 1024 + col];
  else if (row < 2176)  v = pre_w[(row - 2048) * 1024 + col];
  else                  v = gin_w[(row - 2176) * 1024 + col];
  o[i] = f2bf(v);
}

__global__ void bcat_kernel(const float* __restrict__ gout_b, const float* __restrict__ skip_b,
                            const float* __restrict__ pre_b, const float* __restrict__ gin_b,
                            float* __restrict__ dst) {
  int i = blockIdx.x * 256 + threadIdx.x;
  if (i >= 2304) return;
  float v;
  if (i < 1024)      v = gout_b[i];
  else if (i < 2048) v = skip_b[i - 1024];
  else if (i < 2176) v = pre_b[i - 2048];
  else               v = gin_b[i - 2176];
  dst[i] = v;
}

// ---- gamma tables: gam = exp(-|a|+ib), gamL = gam^SEG (double precision once) ----
__global__ void gamma_kernel(const float* __restrict__ a, const float* __restrict__ b,
                             float2* __restrict__ gam, float2* __restrict__ gamL) {
  int tid = blockIdx.x * 256 + threadIdx.x;   // 0..4095
  int m = tid >> 5, c = tid & 31;
  double aa = fabs((double)a[m]);
  double ang = (double)b[c];
  double mag = exp(-aa);
  gam[tid] = make_float2((float)(mag * cos(ang)), (float)(mag * sin(ang)));
  double magL = exp(-aa * (double)SEG);
  double angL = ang * (double)SEG;
  gamL[tid] = make_float2((float)(magL * cos(angL)), (float)(magL * sin(angL)));
}

// ======== GEMM tile body (T2 swizzle, m97 staging, reg-diet for 4 blocks/CU) ========
// K-loop macro shared by both GEMM kernels. Reads As/Bs 128x64 linear LDS tiles.
// Register diet: only 4 B-frags live (16 VGPR); A-frag streamed in i-loop.
#define GEMM_KLOOP(AP, BP, LDK)                                                        \
  for (int k0 = 0; k0 < kloop_end; k0 += 64) {                                         \
    _Pragma("unroll")                                                                  \
    for (int cc = 0; cc < 4; ++cc) {                                                   \
      __builtin_amdgcn_global_load_lds(                                                \
          (const __attribute__((address_space(1))) void*)(AP + k0 + (size_t)cc * 32 * (LDK)), \
          (__attribute__((address_space(3))) void*)(As + cc * 2048 + w * 512), 16, 0, 0);     \
      __builtin_amdgcn_global_load_lds(                                                \
          (const __attribute__((address_space(1))) void*)(BP + k0 + (size_t)cc * 32 * (LDK)), \
          (__attribute__((address_space(3))) void*)(Bs + cc * 2048 + w * 512), 16, 0, 0);     \
    }                                                                                  \
    __syncthreads();                                                                   \
    _Pragma("unroll")                                                                  \
    for (int kk = 0; kk < 2; ++kk) {                                                   \
      const int eb = kk ? e1 : e0;                                                     \
      const char* Bp = (const char*)Bpbase + eb;                                       \
      bf16x8 b0 = *(const bf16x8*)(Bp);                                                \
      bf16x8 b1 = *(const bf16x8*)(Bp + 2048);                                         \
      bf16x8 b2 = *(const bf16x8*)(Bp + 4096);                                         \
      bf16x8 b3 = *(const bf16x8*)(Bp + 6144);                                         \
      const char* Ap = (const char*)Apbase + eb;                                       \
      _Pragma("unroll")                                                                \
      for (int i = 0; i < 4; ++i) {                                                    \
        bf16x8 af = *(const bf16x8*)(Ap + i * 2048);                                   \
        acc[i][0] = __builtin_amdgcn_mfma_f32_16x16x32_bf16(af, b0, acc[i][0], 0, 0, 0);\
        acc[i][1] = __builtin_amdgcn_mfma_f32_16x16x32_bf16(af, b1, acc[i][1], 0, 0, 0);\
        acc[i][2] = __builtin_amdgcn_mfma_f32_16x16x32_bf16(af, b2, acc[i][2], 0, 0, 0);\
        acc[i][3] = __builtin_amdgcn_mfma_f32_16x16x32_bf16(af, b3, acc[i][3], 0, 0, 0);\
      }                                                                                \
    }                                                                                  \
    __syncthreads();                                                                   \
  }

#define GEMM_PREAMBLE                                                                  \
  const int tid = threadIdx.x;                                                         \
  const int lane = tid & 63, w = tid >> 6;                                             \
  const int wr = w >> 1, wc = w & 1;                                                   \
  f32x4 acc[4][4] = {};                                                                \
  const int srow = tid >> 3;                                                           \
  const int ksw = ((tid & 7) ^ (srow & 7)) * 8;                                        \
  const int l15 = lane & 15;                                                           \
  const int krd = (lane >> 4) * 8;                                                     \
  const int rsw = (lane & 7) << 3;                                                     \
  const int e0 = (krd ^ rsw) * 2;                                                      \
  const int e1 = ((32 + krd) ^ rsw) * 2;                                               \
  const unsigned short* Apbase = &As[(wr * 64 + l15) * 64];                            \
  const unsigned short* Bpbase = &Bs[(wc * 64 + l15) * 64];

// ---------------- merged gout/skip/pre/gin GEMM ----------------
// A [T][1024] bf16, B=Wgs [2304][1024] bf16. cols<2048 -> bf16 logits gs[T][2048];
// cols>=2048 -> f32 tmp[T][256]. flat grid 1152 (XCD-partitioned), block 256.
__global__ __launch_bounds__(256, 4) void gemm_gs_kernel(
    const unsigned short* __restrict__ A, const unsigned short* __restrict__ B,
    const float* __restrict__ bias, unsigned short* __restrict__ gs,
    float* __restrict__ tmp) {
  __shared__ __align__(16) unsigned short As[128 * 64];
  __shared__ __align__(16) unsigned short Bs[128 * 64];
  const int xcd = blockIdx.x & 7;
  const int idx = blockIdx.x >> 3;        // 0..143
  const int bn = idx % 18;
  const int bm = xcd * 8 + idx / 18;
  const int n0 = bn * 128, t0 = bm * 128;
  GEMM_PREAMBLE
  const unsigned short* Ab = A + (size_t)(t0 + srow) * 1024 + ksw;
  const unsigned short* Bb = B + (size_t)(n0 + srow) * 1024 + ksw;
  const int kloop_end = 1024;
  GEMM_KLOOP(Ab, Bb, 1024)

  const int rbase = t0 + wr * 64 + ((lane >> 4) * 4);
  const int cbase = n0 + wc * 64 + l15;
#pragma unroll
  for (int j = 0; j < 4; ++j) {
    const int col = cbase + j * 16;
    const float bv = bias[col];
#pragma unroll
    for (int i = 0; i < 4; ++i) {
#pragma unroll
      for (int r = 0; r < 4; ++r) {
        float v = acc[i][j][r] + bv;
        int row = rbase + i * 16 + r;
        if (col < 2048) gs[(size_t)row * 2048 + col] = f2bf(v);
        else            tmp[(size_t)row * 256 + (col - 2048)] = v;
      }
    }
  }
}

// ---------------- split-K mix GEMM: partials[ks][prows][1024] ----------------
// A [prows][8192] bf16, B [1024][8192] bf16.
// xcd_map=1 (full path, 1024 blocks): each XCD owns {ks=xcd>>2, 16-bm slice, all 8 bn}.
__global__ __launch_bounds__(256, 4) void gemm_splitk_kernel(
    const unsigned short* __restrict__ A, const unsigned short* __restrict__ B,
    float* __restrict__ partials, int nbm, int kslice, int prows, int xcd_map) {
  __shared__ __align__(16) unsigned short As[128 * 64];
  __shared__ __align__(16) unsigned short Bs[128 * 64];
  int bm, bn, ks;
  if (xcd_map) {
    const int xcd = blockIdx.x & 7;
    const int idx = blockIdx.x >> 3;      // 0..127
    ks = xcd >> 2;
    bm = (xcd & 3) * 16 + (idx >> 3);
    bn = idx & 7;
  } else {
    const int cpx = gridDim.x >> 3;
    const int wid = (blockIdx.x & 7) * cpx + (blockIdx.x >> 3);
    bm = wid % nbm;
    bn = (wid / nbm) & 7;
    ks = wid / (nbm * 8);
  }
  const int n0 = bn * 128, t0 = bm * 128;
  GEMM_PREAMBLE
  const unsigned short* Ab = A + (size_t)(t0 + srow) * 8192 + ks * kslice + ksw;
  const unsigned short* Bb = B + (size_t)(n0 + srow) * 8192 + ks * kslice + ksw;
  const int kloop_end = kslice;
  GEMM_KLOOP(Ab, Bb, 8192)

  float* Cp = partials + (size_t)ks * prows * 1024;
  const int rbase = t0 + wr * 64 + ((lane >> 4) * 4);
  const int cbase = n0 + wc * 64 + l15;
#pragma unroll
  for (int j = 0; j < 4; ++j) {
    const int col = cbase + j * 16;
#pragma unroll
    for (int i = 0; i < 4; ++i)
#pragma unroll
      for (int r = 0; r < 4; ++r)
        Cp[(size_t)(rbase + i * 16 + r) * 1024 + col] = acc[i][j][r];
  }
}

// fallback reduce: KS_FB partial slabs + bias -> out chunk
__global__ __launch_bounds__(256) void reduce_kernel(const f32x4* __restrict__ partials,
                                                     const f32x4* __restrict__ bias4,
                                                     f32x4* __restrict__ outc) {
  int i = blockIdx.x * 256 + threadIdx.x;
  const size_t stride = (size_t)CHUNK * 256;
  f32x4 s = partials[i];
#pragma unroll
  for (int p = 1; p < KS_FB; ++p) s += partials[(size_t)p * stride + i];
  s += bias4[i & 255];
  outc[i] = s;
}

// ---------------- gated_x = pre * sigmoid(gin) ----------------
__global__ __launch_bounds__(256) void gated_kernel(const float* __restrict__ tmp,
                                                    float* __restrict__ gated) {
  int i = blockIdx.x * 256 + threadIdx.x;
  int t = i >> 7, m = i & 127;
  float p = tmp[t * 256 + m];
  float g = tmp[t * 256 + 128 + m];
  gated[i] = p * sigm(g);
}

// ================= parallel scan =================
__global__ __launch_bounds__(256) void scan_p1_kernel(
    const float* __restrict__ gated, const int* __restrict__ done,
    const float2* __restrict__ gam, const float2* __restrict__ gamL,
    float2* __restrict__ carryA, float2* __restrict__ carryB) {
  int gid = blockIdx.x * 256 + threadIdx.x;
  int seg = gid >> 12, tid = gid & 4095;
  int m = tid >> 5;
  float2 g = gam[tid];
  int t0 = seg * SEG;
  float sr = 0.f, si = 0.f, keep_all = 1.f;
  for (int tt = 0; tt < SEG; ++tt) {
    int t = t0 + tt;
    float xv = gated[t * M_DIM + m];
    bool d = done[t] != 0;
    float pr = d ? 0.f : sr;
    float pi = d ? 0.f : si;
    if (d) keep_all = 0.f;
    sr = fmaf(g.x, pr, fmaf(-g.y, pi, xv));
    si = fmaf(g.y, pr, g.x * pi);
  }
  carryB[(size_t)seg * 4096 + tid] = make_float2(sr, si);
  float2 gL = gamL[tid];
  carryA[(size_t)seg * 4096 + tid] = make_float2(keep_all * gL.x, keep_all * gL.y);
}

__global__ __launch_bounds__(256) void scan_p2_kernel(
    const float2* __restrict__ carryA, float2* __restrict__ carryB,
    const float* __restrict__ s0_re, const float* __restrict__ s0_im) {
  int tid = blockIdx.x * 256 + threadIdx.x;
  float sr = s0_re[tid], si = s0_im[tid];
  for (int p = 0; p < NSEG; ++p) {
    size_t idx = (size_t)p * 4096 + tid;
    float2 A = carryA[idx];
    float2 B = carryB[idx];
    carryB[idx] = make_float2(sr, si);
    float nr = fmaf(A.x, sr, fmaf(-A.y, si, B.x));
    float ni = fmaf(A.y, sr, fmaf(A.x, si, B.y));
    sr = nr; si = ni;
  }
}

__global__ __launch_bounds__(256) void scan_p3_kernel(
    const float* __restrict__ gated, const int* __restrict__ done,
    const float2* __restrict__ gam, const float2* __restrict__ segstart,
    float* __restrict__ out_states, int pair_mode,
    unsigned int* __restrict__ st_bf, int tbase) {
  int gid = blockIdx.x * 256 + threadIdx.x;
  int segl = gid >> 12, tid = gid & 4095;
  int m = tid >> 5;
  int seg = tbase / SEG + segl;
  float2 g = gam[tid];
  float2 s = segstart[(size_t)seg * 4096 + tid];
  float sr = s.x, si = s.y;
  int t0 = seg * SEG;
  for (int tt = 0; tt < SEG; ++tt) {
    int t = t0 + tt;
    float xv = gated[t * M_DIM + m];
    bool d = done[t] != 0;
    float pr = d ? 0.f : sr;
    float pi = d ? 0.f : si;
    sr = fmaf(g.x, pr, fmaf(-g.y, pi, xv));
    si = fmaf(g.y, pr, g.x * pi);
    if (pair_mode) {
      ((float2*)out_states)[(size_t)t * 4096 + tid] = make_float2(sr, si);
    } else {
      out_states[(size_t)t * 4096 + tid] = sr;
    }
    st_bf[(size_t)(t - tbase) * 4096 + tid] =
        (unsigned int)f2bf(sr) | ((unsigned int)f2bf(si) << 16);
  }
}

// ---------------- fused reduce + bias + LN + gates ----------------
__global__ __launch_bounds__(256) void ln_kernel(const float* __restrict__ partials, int nred,
                                                 const float* __restrict__ mixb,
                                                 const unsigned short* __restrict__ gs,
                                                 float* __restrict__ out) {
  const int t = blockIdx.x;
  const int tid = threadIdx.x;
  __shared__ float sm[8];
  const int o = tid * 4;
  f32x4 z;
  if (nred == 0) {
    z = *(const f32x4*)&out[(size_t)t * 1024 + o];
  } else {
    z = *(const f32x4*)&partials[(size_t)t * 1024 + o];
    for (int p = 1; p < nred; ++p)
      z += *(const f32x4*)&partials[(size_t)p * T_DIM * 1024 + (size_t)t * 1024 + o];
    z += *(const f32x4*)&mixb[o];
  }
  ushort4 gu = *(const ushort4*)&gs[(size_t)t * 2048 + o];
  ushort4 su = *(const ushort4*)&gs[(size_t)t * 2048 + 1024 + o];
  float g[4], sk[4], zg[4];
  g[0] = sigm(bf2f(gu.x)); g[1] = sigm(bf2f(gu.y));
  g[2] = sigm(bf2f(gu.z)); g[3] = sigm(bf2f(gu.w));
  sk[0] = bf2f(su.x); sk[1] = bf2f(su.y); sk[2] = bf2f(su.z); sk[3] = bf2f(su.w);
  float sum = 0.f;
#pragma unroll
  for (int j = 0; j < 4; ++j) { zg[j] = z[j] * g[j]; sum += zg[j]; }
#pragma unroll
  for (int off = 32; off > 0; off >>= 1) sum += __shfl_down(sum, off, 64);
  if ((tid & 63) == 0) sm[tid >> 6] = sum;
  __syncthreads();
  const float mu = (sm[0] + sm[1] + sm[2] + sm[3]) * (1.f / 1024.f);
  float sq = 0.f;
#pragma unroll
  for (int j = 0; j < 4; ++j) { float d = zg[j] - mu; sq += d * d; }
#pragma unroll
  for (int off = 32; off > 0; off >>= 1) sq += __shfl_down(sq, off, 64);
  if ((tid & 63) == 0) sm[4 + (tid >> 6)] = sq;
  __syncthreads();
  const float var = (sm[4] + sm[5] + sm[6] + sm[7]) * (1.f / 1024.f);
  const float rstd = 1.f / sqrtf(var + 1e-5f);
  f32x4 res;
#pragma unroll
  for (int j = 0; j < 4; ++j) res[j] = (zg[j] - mu) * rstd + sk[j] * (1.f - g[j]);
  *(f32x4*)&out[(size_t)t * 1024 + o] = res;
}

extern "C" void kernel_launch(void* const* d_in, const int* in_sizes, int n_in,
                              void* d_out, int out_size, void* d_ws, size_t ws_size,
                              hipStream_t stream) {
  const float* x      = (const float*)d_in[0];
  const int*   done   = (const int*)d_in[1];
  const float* s0_re  = (const float*)d_in[2];
  const float* s0_im  = (const float*)d_in[3];
  const float* a      = (const float*)d_in[4];
  const float* b      = (const float*)d_in[5];
  const float* pre_w  = (const float*)d_in[6];
  const float* pre_b  = (const float*)d_in[7];
  const float* gin_w  = (const float*)d_in[8];
  const float* gin_b  = (const float*)d_in[9];
  const float* gout_w = (const float*)d_in[10];
  const float* gout_b = (const float*)d_in[11];
  const float* skip_w = (const float*)d_in[12];
  const float* skip_b = (const float*)d_in[13];
  const float* mix_w  = (const float*)d_in[14];
  const float* mix_b  = (const float*)d_in[15];

  float* out_f = (float*)d_out;                               // [T][1024]
  float* states_f = out_f + (size_t)T_DIM * OUT_DIM;
  const int pair_mode = (out_size >= 75000000) ? 1 : 0;

  char* ws = (char*)d_ws;
  size_t off = 0;
  auto alloc = [&](size_t bytes) {
    void* p = ws + off;
    off = (off + bytes + 255) & ~(size_t)255;
    return p;
  };
  unsigned short* x_bf   = (unsigned short*)alloc((size_t)T_DIM * IN_DIM * 2);     // 16.8 MB
  unsigned short* Bmix   = (unsigned short*)alloc((size_t)OUT_DIM * 8192 * 2);     // 16.8 MB
  unsigned short* Wgs    = (unsigned short*)alloc((size_t)2304 * IN_DIM * 2);      // 4.7 MB
  float* bias_gs         = (float*)alloc(2304 * 4);
  float* tmp_pg          = (float*)alloc((size_t)T_DIM * 256 * 4);                 // 8.4 MB
  float* gated           = (float*)alloc((size_t)T_DIM * M_DIM * 4);               // 4.2 MB
  float2* gam            = (float2*)alloc(4096 * 8);
  float2* gamL           = (float2*)alloc(4096 * 8);
  float2* carryA         = (float2*)alloc((size_t)NSEG * 4096 * 8);                // 4.2 MB
  float2* carryB         = (float2*)alloc((size_t)NSEG * 4096 * 8);                // 4.2 MB
  unsigned short* gs_o   = (unsigned short*)alloc((size_t)T_DIM * 2048 * 2);       // 33.6 MB

  size_t need_main = off + (size_t)T_DIM * 8192 * 2 + (size_t)2 * T_DIM * 1024 * 4 + 1024;
  const int full_path = (ws_size == 0 || ws_size >= need_main) ? 1 : 0;

  dim3 blk(256);
  long nx = (long)T_DIM * IN_DIM;
  f2bf_kernel<<<(unsigned)((nx + 255) / 256), blk, 0, stream>>>(x, x_bf, nx);
  permconv_kernel<<<32768, blk, 0, stream>>>(mix_w, Bmix, 8388608L);
  wcat_kernel<<<9216, blk, 0, stream>>>(gout_w, skip_w, pre_w, gin_w, Wgs);
  bcat_kernel<<<9, blk, 0, stream>>>(gout_b, skip_b, pre_b, gin_b, bias_gs);
  gamma_kernel<<<16, blk, 0, stream>>>(a, b, gam, gamL);

  // merged gout/skip/pre/gin GEMM (flat 1152 blocks, XCD-partitioned)
  gemm_gs_kernel<<<1152, blk, 0, stream>>>(x_bf, Wgs, bias_gs, gs_o, tmp_pg);
  gated_kernel<<<(T_DIM * M_DIM) / 256, blk, 0, stream>>>(tmp_pg, gated);

  // parallel scan P1/P2
  scan_p1_kernel<<<NSEG * 16, blk, 0, stream>>>(gated, done, gam, gamL, carryA, carryB);
  scan_p2_kernel<<<16, blk, 0, stream>>>(carryA, carryB, s0_re, s0_im);

  if (full_path) {
    unsigned short* st_bf = (unsigned short*)alloc((size_t)T_DIM * 8192 * 2);      // 134 MB
    float* partials       = (float*)alloc((size_t)2 * T_DIM * 1024 * 4);           // 67 MB
    scan_p3_kernel<<<NSEG * 16, blk, 0, stream>>>(gated, done, gam, carryB,
                                                  states_f, pair_mode,
                                                  (unsigned int*)st_bf, 0);
    // ONE split-K GEMM: 1024 blocks = exactly 4 blocks/CU, single dispatch phase
    gemm_splitk_kernel<<<1024, blk, 0, stream>>>(st_bf, Bmix, partials,
                                                 64, 4096, T_DIM, 1);
    ln_kernel<<<T_DIM, blk, 0, stream>>>(partials, 2, mix_b, gs_o, out_f);
  } else {
    unsigned short* st_bf = (unsigned short*)alloc((size_t)CHUNK * 8192 * 2);      // 32 MB
    float* partials       = (float*)alloc((size_t)KS_FB * CHUNK * 1024 * 4);       // 32 MB
    for (int ch = 0; ch < T_DIM / CHUNK; ++ch) {
      int tbase = ch * CHUNK;
      scan_p3_kernel<<<(CHUNK / SEG) * 16, blk, 0, stream>>>(gated, done, gam, carryB,
                                                             states_f, pair_mode,
                                                             (unsigned int*)st_bf, tbase);
      gemm_splitk_kernel<<<8 * (CHUNK / 128) * KS_FB, blk, 0, stream>>>(
          st_bf, Bmix, partials, CHUNK / 128, 8192 / KS_FB, CHUNK, 0);
      reduce_kernel<<<CHUNK, blk, 0, stream>>>((const f32x4*)partials, (const f32x4*)mix_b,
                                               (f32x4*)(out_f + (size_t)tbase * OUT_DIM));
    }
    ln_kernel<<<T_DIM, blk, 0, stream>>>(nullptr, 0, mix_b, gs_o, out_f);
  }
  (void)n_in; (void)in_sizes;
}